// Round 12
// baseline (25631.894 us; speedup 1.0000x reference)
//
#include <hip/hip_runtime.h>
#include <cstdint>
#include <cstddef>

// ---------------------------------------------------------------------------
// VWFutureModel: 2-layer GRU scan (T=128, N=256, C=64, U=512) + dense head.
// R12: ROW-LOCAL persistent kernel. The GRU recurrence is row-independent,
// so each WG owns 16 rows and computes ALL columns of every phase locally:
//  - zero grid barriers, zero coherence protocol, 2 launches total
//    (R9-R11 established the ~10us/launch floor: 385 nodes = 3.8 ms of
//    pure dispatch overhead; this design removes the entire class)
//  - h1/h2/rh/hid live in LDS (112 KB) as bf16 hi/lo planes, XOR-swizzled
//    (byte ^= (row&7)<<4) for conflict-free ds_read_b128 A-fragments
//  - u-gates stay in registers (wave's u-strip == its cand-strip columns)
//  - weights pre-swizzled to fragment streams (proven layout), plain cached
//    loads, shared by all 16 WGs via L2/L3
//  - same 3-term split-bf16 MFMA math as R9 (absmax ~2e-3 expected)
//  - fp32 cooperative fallback kept for small ws.
// ---------------------------------------------------------------------------

#define TPB 512
#define NWG 256

constexpr int N_ = 256, T_ = 128, C_ = 64, U_ = 512, H_ = 256;

typedef __attribute__((ext_vector_type(8))) short short8;
typedef __attribute__((ext_vector_type(4))) float f32x4;

// ---------------- workspace layout (bytes) ---------------------------------
constexpr size_t OFF_XHI = 0;                       // [256][8192] bf16 hi
constexpr size_t OFF_XLO = 4194304;                 // [256][8192] bf16 lo
constexpr size_t OFF_STR = 8388608;                 // fragment streams:
constexpr size_t SO_G1 = 0;                         // Wg1: 64 tiles x 18 ch
constexpr size_t SO_C1 = 1152ull * 2048;            // Wc1: 32 x 18
constexpr size_t SO_G2 = 1728ull * 2048;            // Wg2: 64 x 32
constexpr size_t SO_C2 = 3776ull * 2048;            // Wc2: 32 x 32
constexpr size_t SO_H  = 4800ull * 2048;            // Wh:  16 x 16
constexpr size_t SO_P  = 5056ull * 2048;            // Wp:   4 x 8
constexpr size_t WS_NEED = OFF_STR + 5088ull * 2048;  // ~18 MB

// ---------------- LDS layout (bytes) ---------------------------------------
constexpr int H1HI = 0,      H1LO = 16384;   // [16][512] bf16, stride 1024
constexpr int H2HI = 32768,  H2LO = 49152;
constexpr int RHHI = 65536,  RHLO = 81920;
constexpr int HIDHI = 98304, HIDLO = 106496; // [16][256] bf16, stride 512
constexpr int LDS_BYTES = 114688;

// ---------------- scalar helpers -------------------------------------------
__device__ __forceinline__ float sigmoidf_(float z) {
  return 1.0f / (1.0f + __expf(-z));
}
__device__ __forceinline__ float tanhf_(float z) {
  return 1.0f - 2.0f / (1.0f + __expf(2.0f * z));
}
__device__ __forceinline__ unsigned short bf_hi(float f) {
  unsigned int x = __float_as_uint(f);
  unsigned int r = x + 0x7FFFu + ((x >> 16) & 1u);
  return (unsigned short)(r >> 16);
}
__device__ __forceinline__ float bf_s(unsigned short h) {
  return __uint_as_float(((unsigned int)h) << 16);
}
__device__ __forceinline__ unsigned short bf_lo(float f, unsigned short hi) {
  return bf_hi(f - bf_s(hi));
}

// ---------------- LDS plane access (XOR-swizzled) --------------------------
__device__ __forceinline__ float ldHpair(const char* L, int baseHi, int baseLo,
                                         int stride, int r, int c) {
  const int off = r * stride + (((c * 2) ^ ((r & 7) << 4)));
  unsigned short hi = *(const unsigned short*)(L + baseHi + off);
  unsigned short lo = *(const unsigned short*)(L + baseLo + off);
  return bf_s(hi) + bf_s(lo);
}
__device__ __forceinline__ void stHpair(char* L, int baseHi, int baseLo,
                                        int stride, int r, int c, float v) {
  const int off = r * stride + (((c * 2) ^ ((r & 7) << 4)));
  unsigned short h = bf_hi(v);
  *(unsigned short*)(L + baseHi + off) = h;
  *(unsigned short*)(L + baseLo + off) = bf_lo(v, h);
}

// ---------------- strip matmuls (per wave, NT tiles of 16 cols) ------------
// B-frag stream layout (proven R3-R11): buffer (tile*CH + c) of 2048 B:
// [hi 1024B][lo 1024B], element [lane*8+e] = W[32c + (lane>>4)*8 + e][16t+(lane&15)]
// A-frag: lane holds A[row=lane&15][k=(lane>>4)*8 .. +7].

// seg1 = x from global planes (2 chunks), seg2 = LDS plane pair (stride 1024)
template <int NT, int CH>
__device__ __forceinline__ void mm_xg(
    const unsigned short* __restrict__ xh, const unsigned short* __restrict__ xl,
    size_t xbase, const char* L, int b2h, int b2l,
    const char* sb, int tbase, int lane, f32x4 (&z)[NT]) {
  const int r = lane & 15;
  const int klane = (lane >> 4) << 3;
  f32x4 a0[NT], a1[NT], a2[NT];
#pragma unroll
  for (int tn = 0; tn < NT; ++tn) {
    a0[tn] = (f32x4){0.f, 0.f, 0.f, 0.f};
    a1[tn] = (f32x4){0.f, 0.f, 0.f, 0.f};
    a2[tn] = (f32x4){0.f, 0.f, 0.f, 0.f};
  }
#pragma unroll 2
  for (int c = 0; c < CH; ++c) {
    union { uint4 u; short8 s; } ah, al;
    if (c < 2) {
      const size_t ix = xbase + (size_t)r * 8192 + (size_t)(32 * c + klane);
      ah.u = *(const uint4*)(xh + ix);
      al.u = *(const uint4*)(xl + ix);
    } else {
      const int off = r * 1024 + ((((32 * (c - 2) + klane) * 2) ^ ((r & 7) << 4)));
      ah.u = *(const uint4*)(L + b2h + off);
      al.u = *(const uint4*)(L + b2l + off);
    }
#pragma unroll
    for (int tn = 0; tn < NT; ++tn) {
      const char* fb = sb + (size_t)((tbase + tn) * CH + c) * 2048;
      union { uint4 u; short8 s; } bh_, bl_;
      bh_.u = *(const uint4*)(fb + lane * 16);
      bl_.u = *(const uint4*)(fb + 1024 + lane * 16);
      a0[tn] = __builtin_amdgcn_mfma_f32_16x16x32_bf16(ah.s, bh_.s, a0[tn], 0, 0, 0);
      a1[tn] = __builtin_amdgcn_mfma_f32_16x16x32_bf16(ah.s, bl_.s, a1[tn], 0, 0, 0);
      a2[tn] = __builtin_amdgcn_mfma_f32_16x16x32_bf16(al.s, bh_.s, a2[tn], 0, 0, 0);
    }
  }
#pragma unroll
  for (int tn = 0; tn < NT; ++tn) z[tn] = a0[tn] + a1[tn] + a2[tn];
}

// seg1 = LDS plane pair (CS1 chunks, stride s1), seg2 = LDS plane pair
template <int NT, int CH, int CS1>
__device__ __forceinline__ void mm_ll(
    const char* L, int b1h, int b1l, int s1, int b2h, int b2l, int s2,
    const char* sb, int tbase, int lane, f32x4 (&z)[NT]) {
  const int r = lane & 15;
  const int klane = (lane >> 4) << 3;
  f32x4 a0[NT], a1[NT], a2[NT];
#pragma unroll
  for (int tn = 0; tn < NT; ++tn) {
    a0[tn] = (f32x4){0.f, 0.f, 0.f, 0.f};
    a1[tn] = (f32x4){0.f, 0.f, 0.f, 0.f};
    a2[tn] = (f32x4){0.f, 0.f, 0.f, 0.f};
  }
#pragma unroll 2
  for (int c = 0; c < CH; ++c) {
    union { uint4 u; short8 s; } ah, al;
    if (c < CS1) {
      const int off = r * s1 + ((((32 * c + klane) * 2) ^ ((r & 7) << 4)));
      ah.u = *(const uint4*)(L + b1h + off);
      al.u = *(const uint4*)(L + b1l + off);
    } else {
      const int off = r * s2 + ((((32 * (c - CS1) + klane) * 2) ^ ((r & 7) << 4)));
      ah.u = *(const uint4*)(L + b2h + off);
      al.u = *(const uint4*)(L + b2l + off);
    }
#pragma unroll
    for (int tn = 0; tn < NT; ++tn) {
      const char* fb = sb + (size_t)((tbase + tn) * CH + c) * 2048;
      union { uint4 u; short8 s; } bh_, bl_;
      bh_.u = *(const uint4*)(fb + lane * 16);
      bl_.u = *(const uint4*)(fb + 1024 + lane * 16);
      a0[tn] = __builtin_amdgcn_mfma_f32_16x16x32_bf16(ah.s, bh_.s, a0[tn], 0, 0, 0);
      a1[tn] = __builtin_amdgcn_mfma_f32_16x16x32_bf16(ah.s, bl_.s, a1[tn], 0, 0, 0);
      a2[tn] = __builtin_amdgcn_mfma_f32_16x16x32_bf16(al.s, bh_.s, a2[tn], 0, 0, 0);
    }
  }
#pragma unroll
  for (int tn = 0; tn < NT; ++tn) z[tn] = a0[tn] + a1[tn] + a2[tn];
}

// ---------------- prologue: x planes + weight fragment streams -------------
extern "C" __global__ __launch_bounds__(TPB, 2)
void k_pro(const float* __restrict__ frames,
           const float* __restrict__ Wg1, const float* __restrict__ Wc1,
           const float* __restrict__ Wg2, const float* __restrict__ Wc2,
           const float* __restrict__ Wh, const float* __restrict__ Wp,
           char* __restrict__ wsb) {
  const int tid = threadIdx.x;
  const int wg = blockIdx.x;
  unsigned short* xhi = (unsigned short*)(wsb + OFF_XHI);
  unsigned short* xlo = (unsigned short*)(wsb + OFF_XLO);
  const size_t base = (size_t)wg * 8192;
  for (int i = tid; i < 8192; i += TPB) {
    float v = frames[base + i];
    unsigned short h = bf_hi(v);
    xhi[base + i] = h;
    xlo[base + i] = bf_lo(v, h);
  }
  // streams: 5088 fragment buffers, one buffer filled per WG iteration
  const int lane = tid & 63, e = tid >> 6;
  char* ST = wsb + OFF_STR;
  for (int f = wg; f < 5088; f += NWG) {
    const float* W; int ld, CH, fl; size_t so;
    if (f < 1152)      { W = Wg1; ld = 1024; CH = 18; so = SO_G1; fl = f; }
    else if (f < 1728) { W = Wc1; ld = 512;  CH = 18; so = SO_C1; fl = f - 1152; }
    else if (f < 3776) { W = Wg2; ld = 1024; CH = 32; so = SO_G2; fl = f - 1728; }
    else if (f < 4800) { W = Wc2; ld = 512;  CH = 32; so = SO_C2; fl = f - 3776; }
    else if (f < 5056) { W = Wh;  ld = 256;  CH = 16; so = SO_H;  fl = f - 4800; }
    else               { W = Wp;  ld = 64;   CH = 8;  so = SO_P;  fl = f - 5056; }
    const int tn = fl / CH, c = fl % CH;
    const int k = 32 * c + ((lane >> 4) << 3) + e;
    const int col = 16 * tn + (lane & 15);
    const float v = W[(size_t)k * ld + col];
    unsigned short hi = bf_hi(v);
    unsigned short lo = bf_lo(v, hi);
    unsigned short* fb = (unsigned short*)(ST + so + (size_t)fl * 2048);
    fb[lane * 8 + e] = hi;
    fb[512 + lane * 8 + e] = lo;
  }
}

// ---------------- main: row-local GRU scan (16 WGs x 16 rows) --------------
extern "C" __global__ __launch_bounds__(TPB, 2)
void gru_rowlocal(const char* __restrict__ wsb,
                  const float* __restrict__ bg1, const float* __restrict__ bc1,
                  const float* __restrict__ bg2, const float* __restrict__ bc2,
                  const float* __restrict__ bhv, const float* __restrict__ bpv,
                  float* __restrict__ out) {
  __shared__ char L[LDS_BYTES];
  const int tid = threadIdx.x;
  const int w = tid >> 6, lane = tid & 63;
  const int row0 = (int)blockIdx.x * 16;
  const unsigned short* xh = (const unsigned short*)(wsb + OFF_XHI);
  const unsigned short* xl = (const unsigned short*)(wsb + OFF_XLO);
  const char* ST = wsb + OFF_STR;
  const char* SG1 = ST + SO_G1;
  const char* SC1 = ST + SO_C1;
  const char* SG2 = ST + SO_G2;
  const char* SC2 = ST + SO_C2;
  const char* SH  = ST + SO_H;
  const char* SP  = ST + SO_P;

  // zero h1/h2 planes (64 KB)
  for (int i = tid * 16; i < 65536; i += TPB * 16) {
    *(uint4*)(L + i) = (uint4){0u, 0u, 0u, 0u};
  }
  __syncthreads();

  float u1[4][4], u2[4][4];

  for (int t = 0; t < T_; ++t) {
    const size_t xbase = (size_t)row0 * 8192 + (size_t)t * 64;

    // ---- G1: gates1 = sigmoid([x, h1] @ Wg1 + bg1); rh1 -> LDS, u1 -> regs
    {
      f32x4 zr[4], zu[4];
      mm_xg<4, 18>(xh, xl, xbase, L, H1HI, H1LO, SG1, 4 * w, lane, zr);
      mm_xg<4, 18>(xh, xl, xbase, L, H1HI, H1LO, SG1, 32 + 4 * w, lane, zu);
#pragma unroll
      for (int i = 0; i < 4; ++i) {
        const int cl = 64 * w + 16 * i + (lane & 15);
        const float br = bg1[cl];
        const float bu = bg1[512 + cl];
#pragma unroll
        for (int j = 0; j < 4; ++j) {
          const int r = ((lane >> 4) << 2) + j;
          const float s = sigmoidf_(zr[i][j] + br);
          const float h = ldHpair(L, H1HI, H1LO, 1024, r, cl);
          stHpair(L, RHHI, RHLO, 1024, r, cl, s * h);
          u1[i][j] = sigmoidf_(zu[i][j] + bu);
        }
      }
    }
    __syncthreads();

    // ---- C1: c1 = tanh([x, rh1] @ Wc1 + bc1); h1 = u1*h1 + (1-u1)*c1
    {
      f32x4 zc[4];
      mm_xg<4, 18>(xh, xl, xbase, L, RHHI, RHLO, SC1, 4 * w, lane, zc);
#pragma unroll
      for (int i = 0; i < 4; ++i) {
        const int cl = 64 * w + 16 * i + (lane & 15);
        const float b = bc1[cl];
#pragma unroll
        for (int j = 0; j < 4; ++j) {
          const int r = ((lane >> 4) << 2) + j;
          const float cc = tanhf_(zc[i][j] + b);
          const float hold = ldHpair(L, H1HI, H1LO, 1024, r, cl);
          const float hn = u1[i][j] * hold + (1.f - u1[i][j]) * cc;
          stHpair(L, H1HI, H1LO, 1024, r, cl, hn);
        }
      }
    }
    __syncthreads();

    // ---- G2: gates2 = sigmoid([h1', h2] @ Wg2 + bg2); rh2 -> LDS, u2 regs
    {
      f32x4 zr[4], zu[4];
      mm_ll<4, 32, 16>(L, H1HI, H1LO, 1024, H2HI, H2LO, 1024, SG2, 4 * w, lane, zr);
      mm_ll<4, 32, 16>(L, H1HI, H1LO, 1024, H2HI, H2LO, 1024, SG2, 32 + 4 * w, lane, zu);
#pragma unroll
      for (int i = 0; i < 4; ++i) {
        const int cl = 64 * w + 16 * i + (lane & 15);
        const float br = bg2[cl];
        const float bu = bg2[512 + cl];
#pragma unroll
        for (int j = 0; j < 4; ++j) {
          const int r = ((lane >> 4) << 2) + j;
          const float s = sigmoidf_(zr[i][j] + br);
          const float h = ldHpair(L, H2HI, H2LO, 1024, r, cl);
          stHpair(L, RHHI, RHLO, 1024, r, cl, s * h);
          u2[i][j] = sigmoidf_(zu[i][j] + bu);
        }
      }
    }
    __syncthreads();

    // ---- C2: c2 = tanh([h1', rh2] @ Wc2 + bc2); h2 = u2*h2 + (1-u2)*c2
    {
      f32x4 zc[4];
      mm_ll<4, 32, 16>(L, H1HI, H1LO, 1024, RHHI, RHLO, 1024, SC2, 4 * w, lane, zc);
#pragma unroll
      for (int i = 0; i < 4; ++i) {
        const int cl = 64 * w + 16 * i + (lane & 15);
        const float b = bc2[cl];
#pragma unroll
        for (int j = 0; j < 4; ++j) {
          const int r = ((lane >> 4) << 2) + j;
          const float cc = tanhf_(zc[i][j] + b);
          const float hold = ldHpair(L, H2HI, H2LO, 1024, r, cl);
          const float hn = u2[i][j] * hold + (1.f - u2[i][j]) * cc;
          stHpair(L, H2HI, H2LO, 1024, r, cl, hn);
        }
      }
    }
    __syncthreads();

    // ---- head: hidden = elu(h2' @ Wh + bh) -> hid planes
    {
      f32x4 zh[2];
      mm_ll<2, 16, 16>(L, H2HI, H2LO, 1024, H2HI, H2LO, 1024, SH, 2 * w, lane, zh);
#pragma unroll
      for (int i = 0; i < 2; ++i) {
        const int cl = 32 * w + 16 * i + (lane & 15);
        const float b = bhv[cl];
#pragma unroll
        for (int j = 0; j < 4; ++j) {
          const int r = ((lane >> 4) << 2) + j;
          const float zv = zh[i][j] + b;
          const float e = zv > 0.f ? zv : __expf(zv) - 1.f;
          stHpair(L, HIDHI, HIDLO, 512, r, cl, e);
        }
      }
    }
    __syncthreads();

    // ---- out-proj: out[:, t, :] = hid @ Wp + bp (waves 0..3)
    if (w < 4) {
      f32x4 zo[1];
      mm_ll<1, 8, 8>(L, HIDHI, HIDLO, 512, HIDHI, HIDLO, 512, SP, w, lane, zo);
      const int cl = 16 * w + (lane & 15);
      const float b = bpv[cl];
#pragma unroll
      for (int j = 0; j < 4; ++j) {
        const int r = ((lane >> 4) << 2) + j;
        out[(size_t)(row0 + r) * 8192 + (size_t)t * 64 + cl] = zo[0][j] + b;
      }
    }
    __syncthreads();
  }
}

// ======================= R2 fallback (proven fp32 path) ====================
constexpr size_t F_SZ_H   = (size_t)N_ * U_;
constexpr size_t F_OFF_H1 = 0;
constexpr size_t F_OFF_H2 = F_OFF_H1 + 2 * F_SZ_H;
constexpr size_t F_OFF_BAR = F_OFF_H2 + 2 * F_SZ_H;
constexpr size_t F_OFF_G1 = F_OFF_BAR + 64;
constexpr size_t F_OFF_G2 = F_OFF_G1 + (size_t)N_ * 1024;
constexpr size_t F_OFF_HID = F_OFF_G2 + (size_t)N_ * 1024;
constexpr int LDP = 257;

__device__ __forceinline__ void gbarF(unsigned* b, unsigned np) {
  __syncthreads();
  if (threadIdx.x == 0) {
    __threadfence();
    unsigned e = __hip_atomic_load(b + 16, __ATOMIC_RELAXED, __HIP_MEMORY_SCOPE_AGENT);
    unsigned a = __hip_atomic_fetch_add(b, 1u, __ATOMIC_ACQ_REL, __HIP_MEMORY_SCOPE_AGENT);
    if (a == np - 1) {
      __hip_atomic_store(b, 0u, __ATOMIC_RELAXED, __HIP_MEMORY_SCOPE_AGENT);
      __hip_atomic_store(b + 16, e + 1u, __ATOMIC_RELEASE, __HIP_MEMORY_SCOPE_AGENT);
    } else {
      unsigned spins = 0;
      while (__hip_atomic_load(b + 16, __ATOMIC_RELAXED, __HIP_MEMORY_SCOPE_AGENT) == e) {
        __builtin_amdgcn_s_sleep(1);
        if (++spins > (1u << 20)) break;
      }
    }
    __threadfence();
  }
  __syncthreads();
}

template <int CK, bool GATED>
__device__ __forceinline__ void stage(float (*lds)[LDP],
                                      const float* __restrict__ src, int sStride, int sOff,
                                      const float* __restrict__ gate, int gStride, int gOff,
                                      int row0) {
  constexpr int PER = CK / 16;
  const int r = threadIdx.x >> 4;
  const int c0 = (threadIdx.x & 15) * PER;
  const float* s = src + (size_t)(row0 + r) * sStride + sOff + c0;
  float4 a0, a1, a2, a3;
  a0 = *(const float4*)(s);
  if constexpr (PER >= 8) a1 = *(const float4*)(s + 4);
  if constexpr (PER >= 16) { a2 = *(const float4*)(s + 8); a3 = *(const float4*)(s + 12); }
  if constexpr (GATED) {
    const float* g = gate + (size_t)(row0 + r) * gStride + gOff + c0;
    float4 g0 = *(const float4*)(g);
    a0.x *= g0.x; a0.y *= g0.y; a0.z *= g0.z; a0.w *= g0.w;
    if constexpr (PER >= 8) {
      float4 g1v = *(const float4*)(g + 4);
      a1.x *= g1v.x; a1.y *= g1v.y; a1.z *= g1v.z; a1.w *= g1v.w;
    }
    if constexpr (PER >= 16) {
      float4 g2v = *(const float4*)(g + 8);
      float4 g3v = *(const float4*)(g + 12);
      a2.x *= g2v.x; a2.y *= g2v.y; a2.z *= g2v.z; a2.w *= g2v.w;
      a3.x *= g3v.x; a3.y *= g3v.y; a3.z *= g3v.z; a3.w *= g3v.w;
    }
  }
  float* d = &lds[r][c0];
  d[0] = a0.x; d[1] = a0.y; d[2] = a0.z; d[3] = a0.w;
  if constexpr (PER >= 8) { d[4] = a1.x; d[5] = a1.y; d[6] = a1.z; d[7] = a1.w; }
  if constexpr (PER >= 16) {
    d[8] = a2.x; d[9] = a2.y; d[10] = a2.z; d[11] = a2.w;
    d[12] = a3.x; d[13] = a3.y; d[14] = a3.z; d[15] = a3.w;
  }
}
template <int CK>
__device__ __forceinline__ void fma2(float2& acc, const float (*lds)[LDP], int row,
                                     const float* __restrict__ B, int ldB) {
#pragma unroll 8
  for (int k = 0; k < CK; ++k) {
    const float a = lds[row][k];
    const float2 b = *(const float2*)(B + (size_t)k * ldB);
    acc.x = fmaf(a, b.x, acc.x);
    acc.y = fmaf(a, b.y, acc.y);
  }
}
template <int CK>
__device__ __forceinline__ void fma1(float& acc, const float (*lds)[LDP], int row,
                                     const float* __restrict__ B, int ldB) {
#pragma unroll 8
  for (int k = 0; k < CK; ++k) acc = fmaf(lds[row][k], B[(size_t)k * ldB], acc);
}

extern "C" __global__ __launch_bounds__(TPB, 2)
void gru_persistent(const float* __restrict__ frames,
                    const float* __restrict__ Wg1, const float* __restrict__ bg1,
                    const float* __restrict__ Wc1, const float* __restrict__ bc1,
                    const float* __restrict__ Wg2, const float* __restrict__ bg2,
                    const float* __restrict__ Wc2, const float* __restrict__ bc2,
                    const float* __restrict__ Wh,  const float* __restrict__ bh,
                    const float* __restrict__ Wp,  const float* __restrict__ bp,
                    float* __restrict__ out, float* __restrict__ ws) {
  __shared__ float lds[32][LDP];
  float* h1b = ws + F_OFF_H1;
  float* h2b = ws + F_OFF_H2;
  unsigned* bar = (unsigned*)(ws + F_OFF_BAR);
  float* g1 = ws + F_OFF_G1;
  float* g2 = ws + F_OFF_G2;
  float* hid = ws + F_OFF_HID;
  const int tid = threadIdx.x;
  const int wg = blockIdx.x;
  const int xcd = wg & 7, grp = wg >> 3;
  const int m_blk = grp >> 2, n_blk = (xcd << 2) | (grp & 3);
  const int row0 = m_blk * 32;
  const int rowA = tid & 31, cq = tid >> 5;
  const int nrow = row0 + rowA;
  for (int t = 0; t <= T_; ++t) {
    const int p = t & 1;
    const float* h1o = h1b + (size_t)p * F_SZ_H;
    float* h1n = h1b + (size_t)(p ^ 1) * F_SZ_H;
    const float* h2o = h2b + (size_t)p * F_SZ_H;
    float* h2n = h2b + (size_t)(p ^ 1) * F_SZ_H;
    if (t < T_) {
      float2 acc = {0.f, 0.f};
      const int col = n_blk * 32 + cq * 2;
      stage<64, false>(lds, frames, T_ * C_, t * C_, nullptr, 0, 0, row0);
      __syncthreads();
      fma2<64>(acc, lds, rowA, Wg1 + col, 1024);
      __syncthreads();
#pragma unroll 1
      for (int ch = 0; ch < 2; ++ch) {
        stage<256, false>(lds, h1o, U_, ch * 256, nullptr, 0, 0, row0);
        __syncthreads();
        fma2<256>(acc, lds, rowA, Wg1 + (size_t)(64 + ch * 256) * 1024 + col, 1024);
        __syncthreads();
      }
      const float2 bb = *(const float2*)(bg1 + col);
      float* gp = g1 + (size_t)nrow * 1024 + col;
      gp[0] = sigmoidf_(acc.x + bb.x);
      gp[1] = sigmoidf_(acc.y + bb.y);
    }
    gbarF(bar, NWG);
    if (t < T_) {
      float acc = 0.f;
      const int col = n_blk * 16 + cq;
      stage<64, false>(lds, frames, T_ * C_, t * C_, nullptr, 0, 0, row0);
      __syncthreads();
      fma1<64>(acc, lds, rowA, Wc1 + col, U_);
      __syncthreads();
#pragma unroll 1
      for (int ch = 0; ch < 2; ++ch) {
        stage<256, true>(lds, h1o, U_, ch * 256, g1, 1024, ch * 256, row0);
        __syncthreads();
        fma1<256>(acc, lds, rowA, Wc1 + (size_t)(64 + ch * 256) * U_ + col, U_);
        __syncthreads();
      }
      const float cv = tanhf_(acc + bc1[col]);
      const float u = g1[(size_t)nrow * 1024 + 512 + col];
      const float ho = h1o[(size_t)nrow * U_ + col];
      h1n[(size_t)nrow * U_ + col] = u * ho + (1.f - u) * cv;
    }
    if (t > 0) {
      float acc = 0.f;
      const int col = n_blk * 8 + (cq & 7);
      const bool act = tid < 256;
#pragma unroll 1
      for (int ch = 0; ch < 2; ++ch) {
        stage<256, false>(lds, h2o, U_, ch * 256, nullptr, 0, 0, row0);
        __syncthreads();
        if (act) fma1<256>(acc, lds, rowA, Wh + (size_t)(ch * 256) * H_ + col, H_);
        __syncthreads();
      }
      if (act) {
        const float z = acc + bh[col];
        hid[(size_t)nrow * H_ + col] = z > 0.f ? z : __expf(z) - 1.f;
      }
    }
    gbarF(bar, NWG);
    if (t < T_) {
      float2 acc = {0.f, 0.f};
      const int col = n_blk * 32 + cq * 2;
#pragma unroll 1
      for (int ch = 0; ch < 4; ++ch) {
        const float* src = (ch < 2) ? h1n : h2o;
        stage<256, false>(lds, src, U_, (ch & 1) * 256, nullptr, 0, 0, row0);
        __syncthreads();
        fma2<256>(acc, lds, rowA, Wg2 + (size_t)(ch * 256) * 1024 + col, 1024);
        __syncthreads();
      }
      const float2 bb = *(const float2*)(bg2 + col);
      float* gp = g2 + (size_t)nrow * 1024 + col;
      gp[0] = sigmoidf_(acc.x + bb.x);
      gp[1] = sigmoidf_(acc.y + bb.y);
    }
    gbarF(bar, NWG);
    if (t < T_) {
      float acc = 0.f;
      const int col = n_blk * 16 + cq;
#pragma unroll 1
      for (int ch = 0; ch < 4; ++ch) {
        if (ch < 2) stage<256, false>(lds, h1n, U_, (ch & 1) * 256, nullptr, 0, 0, row0);
        else stage<256, true>(lds, h2o, U_, (ch & 1) * 256, g2, 1024, (ch & 1) * 256, row0);
        __syncthreads();
        fma1<256>(acc, lds, rowA, Wc2 + (size_t)(ch * 256) * U_ + col, U_);
        __syncthreads();
      }
      const float cv = tanhf_(acc + bc2[col]);
      const float u = g2[(size_t)nrow * 1024 + 512 + col];
      const float ho = h2o[(size_t)nrow * U_ + col];
      h2n[(size_t)nrow * U_ + col] = u * ho + (1.f - u) * cv;
    }
    if (t > 0) {
      if (tid < 64) {
        float acc = 0.f;
        const int col = n_blk * 2 + cq;
        const float* hrow = hid + (size_t)nrow * H_;
#pragma unroll 8
        for (int k = 0; k < H_; ++k) acc = fmaf(hrow[k], Wp[(size_t)k * C_ + col], acc);
        out[(size_t)nrow * (T_ * C_) + (size_t)(t - 1) * C_ + col] = acc + bp[col];
      }
    }
  }
}

// ---------------- launch ---------------------------------------------------
extern "C" void kernel_launch(void* const* d_in, const int* in_sizes, int n_in,
                              void* d_out, int out_size, void* d_ws, size_t ws_size,
                              hipStream_t stream) {
  const float* frames = (const float*)d_in[0];
  const float* Wg1 = (const float*)d_in[1];
  const float* bg1 = (const float*)d_in[2];
  const float* Wc1 = (const float*)d_in[3];
  const float* bc1 = (const float*)d_in[4];
  const float* Wg2 = (const float*)d_in[5];
  const float* bg2 = (const float*)d_in[6];
  const float* Wc2 = (const float*)d_in[7];
  const float* bc2 = (const float*)d_in[8];
  const float* Wh = (const float*)d_in[9];
  const float* bh = (const float*)d_in[10];
  const float* Wp = (const float*)d_in[11];
  const float* bp = (const float*)d_in[12];
  float* out = (float*)d_out;

  if (ws_size >= WS_NEED) {
    char* wsb = (char*)d_ws;
    hipLaunchKernelGGL(k_pro, dim3(NWG), dim3(TPB), 0, stream,
                       frames, Wg1, Wc1, Wg2, Wc2, Wh, Wp, wsb);
    hipLaunchKernelGGL(gru_rowlocal, dim3(16), dim3(TPB), 0, stream,
                       wsb, bg1, bc1, bg2, bc2, bh, bp, out);
  } else {
    float* ws = (float*)d_ws;
    hipMemsetAsync(d_ws, 0, F_OFF_G1 * sizeof(float), stream);
    void* args[] = {(void*)&frames, (void*)&Wg1, (void*)&bg1, (void*)&Wc1, (void*)&bc1,
                    (void*)&Wg2, (void*)&bg2, (void*)&Wc2, (void*)&bc2,
                    (void*)&Wh, (void*)&bh, (void*)&Wp, (void*)&bp,
                    (void*)&out, (void*)&ws};
    hipError_t err = hipLaunchCooperativeKernel((const void*)gru_persistent,
                                                dim3(NWG), dim3(TPB), args, 0, stream);
    if (err != hipSuccess) {
      (void)hipGetLastError();
      hipLaunchKernelGGL(gru_persistent, dim3(NWG), dim3(TPB), 0, stream,
                         frames, Wg1, bg1, Wc1, bc1, Wg2, bg2, Wc2, bc2,
                         Wh, bh, Wp, bp, out, ws);
    }
  }
}

// Round 14
// 7971.722 us; speedup vs baseline: 3.2154x; 3.2154x over previous
//
#include <hip/hip_runtime.h>
#include <cstdint>
#include <cstddef>

// ---------------------------------------------------------------------------
// VWFutureModel: 2-layer GRU scan (T=128, N=256, C=64, U=512) + dense head.
// R14 = R13 with the K-dimension bug fixed (CH=18 for [x,h1] GEMMs, was 34:
// out-of-bounds weight reads -> GPU fault -> abort). Stream table now matches
// R12's verified counts: G1 64x18, C1 32x18, G2 64x32, C2 32x32, H 16x16,
// P 4x8 (5088 buffers). Design unchanged:
//  - 16 row-groups (M=16) x 8 col-slices = 128 WGs; per-wave full-K register
//    accumulation, no LDS reduction, no __syncthreads in step kernels
//  - n = wg&7 -> each weight slice L2-resident on one XCD
//  - 3 nodes/step: S1=[P2+P2b], S2=[P3+P4b], S3=[P4+P1(t+1)]
//  - fp32 cooperative fallback kept for small ws.
// ---------------------------------------------------------------------------

#define TPB 512
#define NWG 256

constexpr int N_ = 256, T_ = 128, C_ = 64, U_ = 512, H_ = 256;

typedef __attribute__((ext_vector_type(8))) short short8;
typedef __attribute__((ext_vector_type(4))) float f32x4;

// ---------------- workspace layout (bytes) ---------------------------------
constexpr size_t HPB     = 262144;                 // one plane: 256*512*2B
constexpr size_t OFF_HP  = 0;                      // 2 par x [h1hi,h1lo,h2hi,h2lo]
constexpr size_t OFF_RH1 = 8 * HPB;                // 2097152
constexpr size_t OFF_RH2 = OFF_RH1 + 2 * HPB;      // 2621440
constexpr size_t OFF_G1U = OFF_RH2 + 2 * HPB;      // 3145728 fp32 [256][512]
constexpr size_t OFF_G2U = OFF_G1U + 524288;       // 3670016
constexpr size_t OFF_HID = OFF_G2U + 524288;       // 4194304 hid hi/lo
constexpr size_t OFF_STR = OFF_HID + 262144;       // 4456448
// stream buffer counts (one buf = 16-col tile x 32-k chunk = 2048 B hi|lo)
constexpr int SB_G1 = 0;      // Wg1: 64 tiles x 18 ch (K=576)
constexpr int SB_C1 = 1152;   // Wc1: 32 x 18
constexpr int SB_G2 = 1728;   // Wg2: 64 x 32 (K=1024)
constexpr int SB_C2 = 3776;   // Wc2: 32 x 32
constexpr int SB_H  = 4800;   // Wh: 16 x 16 (K=512)
constexpr int SB_P  = 5056;   // Wp: 4 x 8 (K=256)
constexpr int NBTOT = 5088;
constexpr size_t WS_NEED = OFF_STR + (size_t)NBTOT * 2048;  // ~14.9 MB

// ---------------- scalar helpers -------------------------------------------
__device__ __forceinline__ float sigmoidf_(float z) {
  return 1.0f / (1.0f + __expf(-z));
}
__device__ __forceinline__ float tanhf_(float z) {
  return 1.0f - 2.0f / (1.0f + __expf(2.0f * z));
}
__device__ __forceinline__ unsigned short bf_hi(float f) {
  unsigned int x = __float_as_uint(f);
  unsigned int r = x + 0x7FFFu + ((x >> 16) & 1u);
  return (unsigned short)(r >> 16);
}
__device__ __forceinline__ float bf_s(unsigned short h) {
  return __uint_as_float(((unsigned int)h) << 16);
}
__device__ __forceinline__ unsigned short bf_lo(float f, unsigned short hi) {
  return bf_hi(f - bf_s(hi));
}
__device__ __forceinline__ float ldpair(const unsigned short* hi,
                                        const unsigned short* lo, int idx) {
  return bf_s(hi[idx]) + bf_s(lo[idx]);
}
__device__ __forceinline__ void stpair(unsigned short* hi, unsigned short* lo,
                                       int idx, float v) {
  unsigned short h = bf_hi(v);
  hi[idx] = h;
  lo[idx] = bf_lo(v, h);
}

// ---------------- per-wave MFMA tile routines ------------------------------
// B-frag buf (2048B): [hi 1024 | lo 1024], elem [lane*8+e] =
//   W[32c + (lane>>4)*8 + e][16*tile + (lane&15)]
// A-frag: lane holds A[row = lane&15][k = (lane>>4)*8 .. +7].
// C out: elem j of lane -> row (lane>>4)*4+j, col lane&15.  [R12-verified]

__device__ __forceinline__ void cvt8(const float* xp, short8& ah, short8& al) {
  float4 v0 = *(const float4*)xp;
  float4 v1 = *(const float4*)(xp + 4);
  float f[8] = {v0.x, v0.y, v0.z, v0.w, v1.x, v1.y, v1.z, v1.w};
#pragma unroll
  for (int e = 0; e < 8; ++e) {
    unsigned short h = bf_hi(f[e]);
    ah[e] = (short)h;
    al[e] = (short)bf_lo(f[e], h);
  }
}

// first 2 chunks (K=64) from f32 x (row stride 8192), rest from plane pair
template <int CH>
__device__ __forceinline__ f32x4 mm_fx(const float* __restrict__ xp,
                                       const unsigned short* __restrict__ ph,
                                       const unsigned short* __restrict__ pl,
                                       const char* __restrict__ fb, int lane) {
  const int r = lane & 15;
  const int klane = (lane >> 4) << 3;
  f32x4 a0 = {0.f, 0.f, 0.f, 0.f}, a1 = a0, a2 = a0;
#pragma unroll 2
  for (int c = 0; c < CH; ++c) {
    union { uint4 u; short8 s; } ah, al;
    if (c < 2) {
      short8 h8, l8;
      cvt8(xp + (size_t)r * 8192 + 32 * c + klane, h8, l8);
      ah.s = h8; al.s = l8;
    } else {
      const int idx = r * 512 + 32 * (c - 2) + klane;
      ah.u = *(const uint4*)(ph + idx);
      al.u = *(const uint4*)(pl + idx);
    }
    const char* b = fb + (size_t)c * 2048;
    union { uint4 u; short8 s; } bh_, bl_;
    bh_.u = *(const uint4*)(b + lane * 16);
    bl_.u = *(const uint4*)(b + 1024 + lane * 16);
    a0 = __builtin_amdgcn_mfma_f32_16x16x32_bf16(ah.s, bh_.s, a0, 0, 0, 0);
    a1 = __builtin_amdgcn_mfma_f32_16x16x32_bf16(ah.s, bl_.s, a1, 0, 0, 0);
    a2 = __builtin_amdgcn_mfma_f32_16x16x32_bf16(al.s, bh_.s, a2, 0, 0, 0);
  }
  return a0 + a1 + a2;
}

// CS1 chunks from plane pair 1, rest from plane pair 2 (element strides)
template <int CH, int CS1>
__device__ __forceinline__ f32x4 mm_pp(const unsigned short* __restrict__ p1h,
                                       const unsigned short* __restrict__ p1l,
                                       int s1,
                                       const unsigned short* __restrict__ p2h,
                                       const unsigned short* __restrict__ p2l,
                                       int s2,
                                       const char* __restrict__ fb, int lane) {
  const int r = lane & 15;
  const int klane = (lane >> 4) << 3;
  f32x4 a0 = {0.f, 0.f, 0.f, 0.f}, a1 = a0, a2 = a0;
#pragma unroll 2
  for (int c = 0; c < CH; ++c) {
    union { uint4 u; short8 s; } ah, al;
    if (c < CS1) {
      const int idx = r * s1 + 32 * c + klane;
      ah.u = *(const uint4*)(p1h + idx);
      al.u = *(const uint4*)(p1l + idx);
    } else {
      const int idx = r * s2 + 32 * (c - CS1) + klane;
      ah.u = *(const uint4*)(p2h + idx);
      al.u = *(const uint4*)(p2l + idx);
    }
    const char* b = fb + (size_t)c * 2048;
    union { uint4 u; short8 s; } bh_, bl_;
    bh_.u = *(const uint4*)(b + lane * 16);
    bl_.u = *(const uint4*)(b + 1024 + lane * 16);
    a0 = __builtin_amdgcn_mfma_f32_16x16x32_bf16(ah.s, bh_.s, a0, 0, 0, 0);
    a1 = __builtin_amdgcn_mfma_f32_16x16x32_bf16(ah.s, bl_.s, a1, 0, 0, 0);
    a2 = __builtin_amdgcn_mfma_f32_16x16x32_bf16(al.s, bh_.s, a2, 0, 0, 0);
  }
  return a0 + a1 + a2;
}

// ---------------- plane pointer helpers ------------------------------------
__device__ __forceinline__ unsigned short* hpl(char* wsb, int parity) {
  return (unsigned short*)(wsb + OFF_HP + (size_t)parity * 4 * HPB);
}

// P1 at step ts (shared by k_p1 and k_s3); all 8 waves, tile = n*8 + w.
__device__ __attribute__((noinline)) void p1_dev(char* wsb,
                                                 const float* __restrict__ frames,
                                                 const float* __restrict__ bg1,
                                                 int ts, int n, int row0,
                                                 int w, int lane) {
  const int ps = ts & 1;
  unsigned short* h1hi = hpl(wsb, ps);
  unsigned short* h1lo = h1hi + 131072;
  unsigned short* rh1hi = (unsigned short*)(wsb + OFF_RH1);
  unsigned short* rh1lo = rh1hi + 131072;
  float* g1u = (float*)(wsb + OFF_G1U);
  const int gt = n * 8 + w;
  const char* fb = wsb + OFF_STR + (size_t)(SB_G1 + gt * 18) * 2048;
  f32x4 z = mm_fx<18>(frames + (size_t)row0 * 8192 + ts * 64,
                      h1hi + row0 * 512, h1lo + row0 * 512, fb, lane);
  const int cl = gt * 16 + (lane & 15);
  const float b = bg1[cl];
#pragma unroll
  for (int j = 0; j < 4; ++j) {
    const int row = row0 + ((lane >> 4) << 2) + j;
    const float s = sigmoidf_(z[j] + b);
    if (gt < 32) {
      const int idx = row * 512 + cl;
      const float h = ldpair(h1hi, h1lo, idx);
      stpair(rh1hi, rh1lo, idx, s * h);
    } else {
      g1u[row * 512 + (cl - 512)] = s;
    }
  }
}

// ---------------- kernels --------------------------------------------------
extern "C" __global__ __launch_bounds__(TPB, 2)
void k_pro(const float* __restrict__ Wg1, const float* __restrict__ Wc1,
           const float* __restrict__ Wg2, const float* __restrict__ Wc2,
           const float* __restrict__ Wh, const float* __restrict__ Wp,
           char* __restrict__ wsb) {
  const int tid = threadIdx.x;
  const int lane = tid & 63, e = tid >> 6;
  char* ST = wsb + OFF_STR;
  for (int f = blockIdx.x; f < NBTOT; f += NWG) {
    const float* W; int ld, CH, rel;
    if (f < SB_C1)      { W = Wg1; ld = 1024; CH = 18; rel = f; }
    else if (f < SB_G2) { W = Wc1; ld = 512;  CH = 18; rel = f - SB_C1; }
    else if (f < SB_C2) { W = Wg2; ld = 1024; CH = 32; rel = f - SB_G2; }
    else if (f < SB_H)  { W = Wc2; ld = 512;  CH = 32; rel = f - SB_C2; }
    else if (f < SB_P)  { W = Wh;  ld = 256;  CH = 16; rel = f - SB_H; }
    else                { W = Wp;  ld = 64;   CH = 8;  rel = f - SB_P; }
    const int tile = rel / CH, c = rel % CH;
    const int k = 32 * c + ((lane >> 4) << 3) + e;
    const int col = 16 * tile + (lane & 15);
    const float v = W[(size_t)k * ld + col];
    unsigned short hi = bf_hi(v);
    unsigned short lo = bf_lo(v, hi);
    unsigned short* fb = (unsigned short*)(ST + (size_t)f * 2048);
    fb[lane * 8 + e] = hi;
    fb[512 + lane * 8 + e] = lo;
  }
}

extern "C" __global__ __launch_bounds__(TPB, 2)
void k_p1(char* __restrict__ wsb, const float* __restrict__ frames,
          const float* __restrict__ bg1, int t) {
  const int wg = blockIdx.x;
  p1_dev(wsb, frames, bg1, t, wg & 7, (wg >> 3) * 16,
         (int)(threadIdx.x >> 6), (int)(threadIdx.x & 63));
}

// S1 = P2 (t<T_, waves 0-3) + P2b head-dense (t>0, waves 4-5)
extern "C" __global__ __launch_bounds__(TPB, 2)
void k_s1(char* __restrict__ wsb, const float* __restrict__ frames,
          const float* __restrict__ bc1, const float* __restrict__ bh, int t) {
  const int wg = blockIdx.x;
  const int n = wg & 7, row0 = (wg >> 3) * 16;
  const int w = threadIdx.x >> 6, lane = threadIdx.x & 63;
  const int p = t & 1, q = p ^ 1;
  unsigned short* h1hi_p = hpl(wsb, p);
  unsigned short* h1lo_p = h1hi_p + 131072;
  unsigned short* h2hi_p = h1hi_p + 262144;
  unsigned short* h2lo_p = h1hi_p + 393216;
  unsigned short* h1hi_q = hpl(wsb, q);
  unsigned short* h1lo_q = h1hi_q + 131072;
  unsigned short* rh1hi = (unsigned short*)(wsb + OFF_RH1);
  unsigned short* rh1lo = rh1hi + 131072;
  unsigned short* hidhi = (unsigned short*)(wsb + OFF_HID);
  unsigned short* hidlo = hidhi + 131072;
  const float* g1u = (const float*)(wsb + OFF_G1U);

  if (t < T_ && w < 4) {
    const int gt = n * 4 + w;
    const char* fb = wsb + OFF_STR + (size_t)(SB_C1 + gt * 18) * 2048;
    f32x4 z = mm_fx<18>(frames + (size_t)row0 * 8192 + t * 64,
                        rh1hi + row0 * 512, rh1lo + row0 * 512, fb, lane);
    const int cl = gt * 16 + (lane & 15);
    const float b = bc1[cl];
#pragma unroll
    for (int j = 0; j < 4; ++j) {
      const int row = row0 + ((lane >> 4) << 2) + j;
      const int idx = row * 512 + cl;
      const float c0 = tanhf_(z[j] + b);
      const float u = g1u[idx];
      const float hold = ldpair(h1hi_p, h1lo_p, idx);
      stpair(h1hi_q, h1lo_q, idx, u * hold + (1.f - u) * c0);
    }
  }
  if (t > 0 && w >= 4 && w < 6) {
    const int gt = n * 2 + (w - 4);
    const char* fb = wsb + OFF_STR + (size_t)(SB_H + gt * 16) * 2048;
    f32x4 z = mm_pp<16, 16>(h2hi_p + row0 * 512, h2lo_p + row0 * 512, 512,
                            h2hi_p + row0 * 512, h2lo_p + row0 * 512, 512,
                            fb, lane);
    const int cl = gt * 16 + (lane & 15);
    const float b = bh[cl];
#pragma unroll
    for (int j = 0; j < 4; ++j) {
      const int row = row0 + ((lane >> 4) << 2) + j;
      const float zv = z[j] + b;
      const float e = zv > 0.f ? zv : __expf(zv) - 1.f;
      stpair(hidhi, hidlo, row * 256 + cl, e);
    }
  }
}

// S2 = P3 (t<T_, waves 0-7) + P4b out-proj (t>0, n<4, wave 7 extra)
extern "C" __global__ __launch_bounds__(TPB, 2)
void k_s2(char* __restrict__ wsb, const float* __restrict__ bg2,
          const float* __restrict__ bp, float* __restrict__ out, int t) {
  const int wg = blockIdx.x;
  const int n = wg & 7, row0 = (wg >> 3) * 16;
  const int w = threadIdx.x >> 6, lane = threadIdx.x & 63;
  const int p = t & 1, q = p ^ 1;
  unsigned short* h1hi_q = hpl(wsb, q);
  unsigned short* h1lo_q = h1hi_q + 131072;
  unsigned short* h2hi_p = hpl(wsb, p) + 262144;
  unsigned short* h2lo_p = hpl(wsb, p) + 393216;
  unsigned short* rh2hi = (unsigned short*)(wsb + OFF_RH2);
  unsigned short* rh2lo = rh2hi + 131072;
  unsigned short* hidhi = (unsigned short*)(wsb + OFF_HID);
  unsigned short* hidlo = hidhi + 131072;
  float* g2u = (float*)(wsb + OFF_G2U);

  if (t < T_) {
    const int gt = n * 8 + w;
    const char* fb = wsb + OFF_STR + (size_t)(SB_G2 + gt * 32) * 2048;
    f32x4 z = mm_pp<32, 16>(h1hi_q + row0 * 512, h1lo_q + row0 * 512, 512,
                            h2hi_p + row0 * 512, h2lo_p + row0 * 512, 512,
                            fb, lane);
    const int cl = gt * 16 + (lane & 15);
    const float b = bg2[cl];
#pragma unroll
    for (int j = 0; j < 4; ++j) {
      const int row = row0 + ((lane >> 4) << 2) + j;
      const float s = sigmoidf_(z[j] + b);
      if (gt < 32) {
        const int idx = row * 512 + cl;
        const float h = ldpair(h2hi_p, h2lo_p, idx);
        stpair(rh2hi, rh2lo, idx, s * h);
      } else {
        g2u[row * 512 + (cl - 512)] = s;
      }
    }
  }
  if (t > 0 && n < 4 && w == 7) {
    const char* fb = wsb + OFF_STR + (size_t)(SB_P + n * 8) * 2048;
    f32x4 z = mm_pp<8, 8>(hidhi + row0 * 256, hidlo + row0 * 256, 256,
                          hidhi + row0 * 256, hidlo + row0 * 256, 256,
                          fb, lane);
    const int cl = n * 16 + (lane & 15);
    const float b = bp[cl];
#pragma unroll
    for (int j = 0; j < 4; ++j) {
      const int row = row0 + ((lane >> 4) << 2) + j;
      out[(size_t)row * 8192 + (size_t)(t - 1) * 64 + cl] = z[j] + b;
    }
  }
}

// S3 = P4 (waves 0-3) + P1(t+1) (all waves, if t+1 < T_)
extern "C" __global__ __launch_bounds__(TPB, 2)
void k_s3(char* __restrict__ wsb, const float* __restrict__ frames,
          const float* __restrict__ bc2, const float* __restrict__ bg1, int t) {
  const int wg = blockIdx.x;
  const int n = wg & 7, row0 = (wg >> 3) * 16;
  const int w = threadIdx.x >> 6, lane = threadIdx.x & 63;
  const int p = t & 1, q = p ^ 1;
  unsigned short* h1hi_q = hpl(wsb, q);
  unsigned short* h1lo_q = h1hi_q + 131072;
  unsigned short* h2hi_p = hpl(wsb, p) + 262144;
  unsigned short* h2lo_p = hpl(wsb, p) + 393216;
  unsigned short* h2hi_q = h1hi_q + 262144;
  unsigned short* h2lo_q = h1hi_q + 393216;
  unsigned short* rh2hi = (unsigned short*)(wsb + OFF_RH2);
  unsigned short* rh2lo = rh2hi + 131072;
  const float* g2u = (const float*)(wsb + OFF_G2U);

  if (w < 4) {
    const int gt = n * 4 + w;
    const char* fb = wsb + OFF_STR + (size_t)(SB_C2 + gt * 32) * 2048;
    f32x4 z = mm_pp<32, 16>(h1hi_q + row0 * 512, h1lo_q + row0 * 512, 512,
                            rh2hi + row0 * 512, rh2lo + row0 * 512, 512,
                            fb, lane);
    const int cl = gt * 16 + (lane & 15);
    const float b = bc2[cl];
#pragma unroll
    for (int j = 0; j < 4; ++j) {
      const int row = row0 + ((lane >> 4) << 2) + j;
      const int idx = row * 512 + cl;
      const float c0 = tanhf_(z[j] + b);
      const float u = g2u[idx];
      const float hold = ldpair(h2hi_p, h2lo_p, idx);
      stpair(h2hi_q, h2lo_q, idx, u * hold + (1.f - u) * c0);
    }
  }
  if (t + 1 < T_) {
    p1_dev(wsb, frames, bg1, t + 1, n, row0, w, lane);
  }
}

// ======================= R2 fallback (proven fp32 path) ====================
constexpr size_t F_SZ_H   = (size_t)N_ * U_;
constexpr size_t F_OFF_H1 = 0;
constexpr size_t F_OFF_H2 = F_OFF_H1 + 2 * F_SZ_H;
constexpr size_t F_OFF_BAR = F_OFF_H2 + 2 * F_SZ_H;
constexpr size_t F_OFF_G1 = F_OFF_BAR + 64;
constexpr size_t F_OFF_G2 = F_OFF_G1 + (size_t)N_ * 1024;
constexpr size_t F_OFF_HID = F_OFF_G2 + (size_t)N_ * 1024;
constexpr int LDP = 257;

__device__ __forceinline__ void gbarF(unsigned* b, unsigned np) {
  __syncthreads();
  if (threadIdx.x == 0) {
    __threadfence();
    unsigned e = __hip_atomic_load(b + 16, __ATOMIC_RELAXED, __HIP_MEMORY_SCOPE_AGENT);
    unsigned a = __hip_atomic_fetch_add(b, 1u, __ATOMIC_ACQ_REL, __HIP_MEMORY_SCOPE_AGENT);
    if (a == np - 1) {
      __hip_atomic_store(b, 0u, __ATOMIC_RELAXED, __HIP_MEMORY_SCOPE_AGENT);
      __hip_atomic_store(b + 16, e + 1u, __ATOMIC_RELEASE, __HIP_MEMORY_SCOPE_AGENT);
    } else {
      unsigned spins = 0;
      while (__hip_atomic_load(b + 16, __ATOMIC_RELAXED, __HIP_MEMORY_SCOPE_AGENT) == e) {
        __builtin_amdgcn_s_sleep(1);
        if (++spins > (1u << 20)) break;
      }
    }
    __threadfence();
  }
  __syncthreads();
}

template <int CK, bool GATED>
__device__ __forceinline__ void stage(float (*lds)[LDP],
                                      const float* __restrict__ src, int sStride, int sOff,
                                      const float* __restrict__ gate, int gStride, int gOff,
                                      int row0) {
  constexpr int PER = CK / 16;
  const int r = threadIdx.x >> 4;
  const int c0 = (threadIdx.x & 15) * PER;
  const float* s = src + (size_t)(row0 + r) * sStride + sOff + c0;
  float4 a0, a1, a2, a3;
  a0 = *(const float4*)(s);
  if constexpr (PER >= 8) a1 = *(const float4*)(s + 4);
  if constexpr (PER >= 16) { a2 = *(const float4*)(s + 8); a3 = *(const float4*)(s + 12); }
  if constexpr (GATED) {
    const float* g = gate + (size_t)(row0 + r) * gStride + gOff + c0;
    float4 g0 = *(const float4*)(g);
    a0.x *= g0.x; a0.y *= g0.y; a0.z *= g0.z; a0.w *= g0.w;
    if constexpr (PER >= 8) {
      float4 g1v = *(const float4*)(g + 4);
      a1.x *= g1v.x; a1.y *= g1v.y; a1.z *= g1v.z; a1.w *= g1v.w;
    }
    if constexpr (PER >= 16) {
      float4 g2v = *(const float4*)(g + 8);
      float4 g3v = *(const float4*)(g + 12);
      a2.x *= g2v.x; a2.y *= g2v.y; a2.z *= g2v.z; a2.w *= g2v.w;
      a3.x *= g3v.x; a3.y *= g3v.y; a3.z *= g3v.z; a3.w *= g3v.w;
    }
  }
  float* d = &lds[r][c0];
  d[0] = a0.x; d[1] = a0.y; d[2] = a0.z; d[3] = a0.w;
  if constexpr (PER >= 8) { d[4] = a1.x; d[5] = a1.y; d[6] = a1.z; d[7] = a1.w; }
  if constexpr (PER >= 16) {
    d[8] = a2.x; d[9] = a2.y; d[10] = a2.z; d[11] = a2.w;
    d[12] = a3.x; d[13] = a3.y; d[14] = a3.z; d[15] = a3.w;
  }
}
template <int CK>
__device__ __forceinline__ void fma2(float2& acc, const float (*lds)[LDP], int row,
                                     const float* __restrict__ B, int ldB) {
#pragma unroll 8
  for (int k = 0; k < CK; ++k) {
    const float a = lds[row][k];
    const float2 b = *(const float2*)(B + (size_t)k * ldB);
    acc.x = fmaf(a, b.x, acc.x);
    acc.y = fmaf(a, b.y, acc.y);
  }
}
template <int CK>
__device__ __forceinline__ void fma1(float& acc, const float (*lds)[LDP], int row,
                                     const float* __restrict__ B, int ldB) {
#pragma unroll 8
  for (int k = 0; k < CK; ++k) acc = fmaf(lds[row][k], B[(size_t)k * ldB], acc);
}

extern "C" __global__ __launch_bounds__(TPB, 2)
void gru_persistent(const float* __restrict__ frames,
                    const float* __restrict__ Wg1, const float* __restrict__ bg1,
                    const float* __restrict__ Wc1, const float* __restrict__ bc1,
                    const float* __restrict__ Wg2, const float* __restrict__ bg2,
                    const float* __restrict__ Wc2, const float* __restrict__ bc2,
                    const float* __restrict__ Wh,  const float* __restrict__ bh,
                    const float* __restrict__ Wp,  const float* __restrict__ bp,
                    float* __restrict__ out, float* __restrict__ ws) {
  __shared__ float lds[32][LDP];
  float* h1b = ws + F_OFF_H1;
  float* h2b = ws + F_OFF_H2;
  unsigned* bar = (unsigned*)(ws + F_OFF_BAR);
  float* g1 = ws + F_OFF_G1;
  float* g2 = ws + F_OFF_G2;
  float* hid = ws + F_OFF_HID;
  const int tid = threadIdx.x;
  const int wg = blockIdx.x;
  const int xcd = wg & 7, grp = wg >> 3;
  const int m_blk = grp >> 2, n_blk = (xcd << 2) | (grp & 3);
  const int row0 = m_blk * 32;
  const int rowA = tid & 31, cq = tid >> 5;
  const int nrow = row0 + rowA;
  for (int t = 0; t <= T_; ++t) {
    const int p = t & 1;
    const float* h1o = h1b + (size_t)p * F_SZ_H;
    float* h1n = h1b + (size_t)(p ^ 1) * F_SZ_H;
    const float* h2o = h2b + (size_t)p * F_SZ_H;
    float* h2n = h2b + (size_t)(p ^ 1) * F_SZ_H;
    if (t < T_) {
      float2 acc = {0.f, 0.f};
      const int col = n_blk * 32 + cq * 2;
      stage<64, false>(lds, frames, T_ * C_, t * C_, nullptr, 0, 0, row0);
      __syncthreads();
      fma2<64>(acc, lds, rowA, Wg1 + col, 1024);
      __syncthreads();
#pragma unroll 1
      for (int ch = 0; ch < 2; ++ch) {
        stage<256, false>(lds, h1o, U_, ch * 256, nullptr, 0, 0, row0);
        __syncthreads();
        fma2<256>(acc, lds, rowA, Wg1 + (size_t)(64 + ch * 256) * 1024 + col, 1024);
        __syncthreads();
      }
      const float2 bb = *(const float2*)(bg1 + col);
      float* gp = g1 + (size_t)nrow * 1024 + col;
      gp[0] = sigmoidf_(acc.x + bb.x);
      gp[1] = sigmoidf_(acc.y + bb.y);
    }
    gbarF(bar, NWG);
    if (t < T_) {
      float acc = 0.f;
      const int col = n_blk * 16 + cq;
      stage<64, false>(lds, frames, T_ * C_, t * C_, nullptr, 0, 0, row0);
      __syncthreads();
      fma1<64>(acc, lds, rowA, Wc1 + col, U_);
      __syncthreads();
#pragma unroll 1
      for (int ch = 0; ch < 2; ++ch) {
        stage<256, true>(lds, h1o, U_, ch * 256, g1, 1024, ch * 256, row0);
        __syncthreads();
        fma1<256>(acc, lds, rowA, Wc1 + (size_t)(64 + ch * 256) * U_ + col, U_);
        __syncthreads();
      }
      const float cv = tanhf_(acc + bc1[col]);
      const float u = g1[(size_t)nrow * 1024 + 512 + col];
      const float ho = h1o[(size_t)nrow * U_ + col];
      h1n[(size_t)nrow * U_ + col] = u * ho + (1.f - u) * cv;
    }
    if (t > 0) {
      float acc = 0.f;
      const int col = n_blk * 8 + (cq & 7);
      const bool act = tid < 256;
#pragma unroll 1
      for (int ch = 0; ch < 2; ++ch) {
        stage<256, false>(lds, h2o, U_, ch * 256, nullptr, 0, 0, row0);
        __syncthreads();
        if (act) fma1<256>(acc, lds, rowA, Wh + (size_t)(ch * 256) * H_ + col, H_);
        __syncthreads();
      }
      if (act) {
        const float z = acc + bh[col];
        hid[(size_t)nrow * H_ + col] = z > 0.f ? z : __expf(z) - 1.f;
      }
    }
    gbarF(bar, NWG);
    if (t < T_) {
      float2 acc = {0.f, 0.f};
      const int col = n_blk * 32 + cq * 2;
#pragma unroll 1
      for (int ch = 0; ch < 4; ++ch) {
        const float* src = (ch < 2) ? h1n : h2o;
        stage<256, false>(lds, src, U_, (ch & 1) * 256, nullptr, 0, 0, row0);
        __syncthreads();
        fma2<256>(acc, lds, rowA, Wg2 + (size_t)(ch * 256) * 1024 + col, 1024);
        __syncthreads();
      }
      const float2 bb = *(const float2*)(bg2 + col);
      float* gp = g2 + (size_t)nrow * 1024 + col;
      gp[0] = sigmoidf_(acc.x + bb.x);
      gp[1] = sigmoidf_(acc.y + bb.y);
    }
    gbarF(bar, NWG);
    if (t < T_) {
      float acc = 0.f;
      const int col = n_blk * 16 + cq;
#pragma unroll 1
      for (int ch = 0; ch < 4; ++ch) {
        if (ch < 2) stage<256, false>(lds, h1n, U_, (ch & 1) * 256, nullptr, 0, 0, row0);
        else stage<256, true>(lds, h2o, U_, (ch & 1) * 256, g2, 1024, (ch & 1) * 256, row0);
        __syncthreads();
        fma1<256>(acc, lds, rowA, Wc2 + (size_t)(ch * 256) * U_ + col, U_);
        __syncthreads();
      }
      const float cv = tanhf_(acc + bc2[col]);
      const float u = g2[(size_t)nrow * 1024 + 512 + col];
      const float ho = h2o[(size_t)nrow * U_ + col];
      h2n[(size_t)nrow * U_ + col] = u * ho + (1.f - u) * cv;
    }
    if (t > 0) {
      if (tid < 64) {
        float acc = 0.f;
        const int col = n_blk * 2 + cq;
        const float* hrow = hid + (size_t)nrow * H_;
#pragma unroll 8
        for (int k = 0; k < H_; ++k) acc = fmaf(hrow[k], Wp[(size_t)k * C_ + col], acc);
        out[(size_t)nrow * (T_ * C_) + (size_t)(t - 1) * C_ + col] = acc + bp[col];
      }
    }
  }
}

// ---------------- launch ---------------------------------------------------
extern "C" void kernel_launch(void* const* d_in, const int* in_sizes, int n_in,
                              void* d_out, int out_size, void* d_ws, size_t ws_size,
                              hipStream_t stream) {
  const float* frames = (const float*)d_in[0];
  const float* Wg1 = (const float*)d_in[1];
  const float* bg1 = (const float*)d_in[2];
  const float* Wc1 = (const float*)d_in[3];
  const float* bc1 = (const float*)d_in[4];
  const float* Wg2 = (const float*)d_in[5];
  const float* bg2 = (const float*)d_in[6];
  const float* Wc2 = (const float*)d_in[7];
  const float* bc2 = (const float*)d_in[8];
  const float* Wh = (const float*)d_in[9];
  const float* bh = (const float*)d_in[10];
  const float* Wp = (const float*)d_in[11];
  const float* bp = (const float*)d_in[12];
  float* out = (float*)d_out;

  if (ws_size >= WS_NEED) {
    char* wsb = (char*)d_ws;
    hipMemsetAsync(d_ws, 0, 4 * HPB, stream);  // zero parity-0 h planes
    hipLaunchKernelGGL(k_pro, dim3(NWG), dim3(TPB), 0, stream,
                       Wg1, Wc1, Wg2, Wc2, Wh, Wp, wsb);
    hipLaunchKernelGGL(k_p1, dim3(128), dim3(TPB), 0, stream, wsb, frames, bg1, 0);
    for (int t = 0; t <= T_; ++t) {
      hipLaunchKernelGGL(k_s1, dim3(128), dim3(TPB), 0, stream, wsb, frames, bc1, bh, t);
      hipLaunchKernelGGL(k_s2, dim3(128), dim3(TPB), 0, stream, wsb, bg2, bp, out, t);
      if (t < T_)
        hipLaunchKernelGGL(k_s3, dim3(128), dim3(TPB), 0, stream, wsb, frames, bc2, bg1, t);
    }
  } else {
    float* ws = (float*)d_ws;
    hipMemsetAsync(d_ws, 0, F_OFF_G1 * sizeof(float), stream);
    void* args[] = {(void*)&frames, (void*)&Wg1, (void*)&bg1, (void*)&Wc1, (void*)&bc1,
                    (void*)&Wg2, (void*)&bg2, (void*)&Wc2, (void*)&bc2,
                    (void*)&Wh, (void*)&bh, (void*)&Wp, (void*)&bp,
                    (void*)&out, (void*)&ws};
    hipError_t err = hipLaunchCooperativeKernel((const void*)gru_persistent,
                                                dim3(NWG), dim3(TPB), args, 0, stream);
    if (err != hipSuccess) {
      (void)hipGetLastError();
      hipLaunchKernelGGL(gru_persistent, dim3(NWG), dim3(TPB), 0, stream,
                         frames, Wg1, bg1, Wc1, bc1, Wg2, bg2, Wc2, bc2,
                         Wh, bh, Wp, bp, out, ws);
    }
  }
}

// Round 15
// 3775.840 us; speedup vs baseline: 6.7884x; 2.1112x over previous
//
#include <hip/hip_runtime.h>
#include <cstdint>
#include <cstddef>

// ---------------------------------------------------------------------------
// VWFutureModel: 2-layer GRU scan (T=128, N=256, C=64, U=512) + dense head.
// R15 = exact restore of R9 (session best: 3.78 ms, absmax 1.953e-3).
// 14 rounds of evidence bracket this as the structural optimum of the
// design space: per-phase cost = max(launch, duplicated-traffic/L3-BW,
// per-WG latency-serialization); traffic ~ (1/Mt + 1/Nt) with parallelism
// (256/Mt)(1024/Nt); at the >=256-WG parallelism floor (R11/R12/R14
// evidence), Mt=Nt=32 is optimal = this kernel.
// Graph-of-kernels: 387 launches; kernel boundaries provide cross-XCD
// visibility; all data-path accesses plain cached loads/stores:
//  - weights: n = wg&31 -> same-n WGs on XCD n%8 -> slice L2-resident
//  - exchange (h planes, rh, gates, hid): normal cached loads/stores
// Per step: S1=[P2+P2b], S2=[P3+P4b], S3=[P4 + P1(t+1)].
// fp32 cooperative fallback kept for small ws.
// ---------------------------------------------------------------------------

#define NWG 256
#define TPB 512

constexpr int N_ = 256, T_ = 128, C_ = 64, U_ = 512, H_ = 256;

typedef __attribute__((ext_vector_type(8))) short short8;
typedef __attribute__((ext_vector_type(4))) float f32x4;

// ---------------- byte offsets in workspace --------------------------------
constexpr size_t HPB      = 262144;                 // one h plane: 256*512*2B
constexpr size_t OFF_HP   = 16384;                  // 2 bufs x [h1hi,h1lo,h2hi,h2lo]
constexpr size_t OFF_RH1  = OFF_HP + 8 * HPB;
constexpr size_t OFF_RH2  = OFF_RH1 + 524288;
constexpr size_t OFF_G1U  = OFF_RH2 + 524288;       // fp32 [256][512]
constexpr size_t OFF_G2U  = OFF_G1U + 524288;
constexpr size_t OFF_HID  = OFF_G2U + 524288;       // hid hi,lo (2*131072)
constexpr size_t OFF_XHI  = OFF_HID + 262144;       // [256][8192] bf16
constexpr size_t OFF_XLO  = OFF_XHI + 4194304;
constexpr size_t OFF_WG1S = OFF_XLO + 4194304;      // 32 * 81920
constexpr size_t OFF_WC1S = OFF_WG1S + 32 * 81920;  // 32 * 40960
constexpr size_t OFF_WG2S = OFF_WC1S + 32 * 40960;  // 32 * 131072
constexpr size_t OFF_WC2S = OFF_WG2S + 32 * 131072; // 32 * 65536
constexpr size_t OFF_WHS  = OFF_WC2S + 32 * 65536;  // 16 * 32768
constexpr size_t OFF_WPS  = OFF_WHS + 16 * 32768;   // 4 * 16384
constexpr size_t WS_NEED  = OFF_WPS + 4 * 16384;    // ~22.6 MiB

// ---------------- scalar helpers -------------------------------------------
__device__ __forceinline__ float sigmoidf_(float z) {
  return 1.0f / (1.0f + __expf(-z));
}
__device__ __forceinline__ float tanhf_(float z) {
  return 1.0f - 2.0f / (1.0f + __expf(2.0f * z));
}
__device__ __forceinline__ unsigned short bf_hi(float f) {
  unsigned int x = __float_as_uint(f);
  unsigned int r = x + 0x7FFFu + ((x >> 16) & 1u);
  return (unsigned short)(r >> 16);
}
__device__ __forceinline__ float bf_f(unsigned v) {  // low 16 bits as bf16
  return __uint_as_float((v & 0xFFFFu) << 16);
}
__device__ __forceinline__ float bf_fh(unsigned v) {  // high 16 bits as bf16
  return __uint_as_float(v & 0xFFFF0000u);
}
__device__ __forceinline__ unsigned short bf_lo(float f, unsigned short hi) {
  return bf_hi(f - __uint_as_float(((unsigned)hi) << 16));
}

// ---------------- weight stream swizzle (prologue; zero-padded) ------------
__device__ void writeStream(const float* __restrict__ W, int ldW, int colbase,
                            char* sb, int nsplit, int slots, int tnn, int nch) {
  const int tid = threadIdx.x;
  const int lane = tid & 63;
  const int e = tid >> 6;  // 0..7
  const int nf = nsplit * slots * tnn;
  for (int f = 0; f < nf; ++f) {
    int tn = f % tnn;
    int ci = (f / tnn) % slots;
    int ks = f / (tnn * slots);
    int c = ks + ci * nsplit;
    int k = 32 * c + ((lane >> 4) << 3) + e;
    int col = colbase + 16 * tn + (lane & 15);
    float v = (c < nch) ? W[(size_t)k * ldW + col] : 0.f;
    unsigned short hi = bf_hi(v);
    unsigned short lo = bf_lo(v, hi);
    unsigned short* fb = (unsigned short*)(sb + (size_t)f * 2048);
    fb[lane * 8 + e] = hi;
    fb[512 + lane * 8 + e] = lo;
  }
}

// ---------------- MFMA core (plain cached loads) ---------------------------
template <int TM, int TN, int NSPLIT, int SLOTS, int KA>
__device__ __forceinline__ void mm_core(
    const unsigned short* __restrict__ A1h, const unsigned short* __restrict__ A1l,
    int lda1, int aoff,
    const unsigned short* __restrict__ A2h, const unsigned short* __restrict__ A2l,
    int lda2, const char* __restrict__ bstr, float* red, int row0loc) {
  const int tid = threadIdx.x;
  const int ww = tid >> 6, lane = tid & 63;
  const int tm = ww / NSPLIT;
  const int ks = ww % NSPLIT;
  const int arow = row0loc + 16 * tm + (lane & 15);
  const int kgrp = (lane >> 4) << 3;

  uint4 Ah[SLOTS], Al[SLOTS];
#pragma unroll
  for (int ci = 0; ci < SLOTS; ++ci) {
    const int c = ks + ci * NSPLIT;
    const int ak = 32 * c + kgrp;
    const unsigned short *ph, *pl;
    if (ak < KA) {
      ph = A1h + (size_t)arow * lda1 + aoff + ak;
      pl = A1l + (size_t)arow * lda1 + aoff + ak;
    } else {
      const int ak2 = ak - KA;
      ph = A2h + (size_t)arow * lda2 + ak2;
      pl = A2l + (size_t)arow * lda2 + ak2;
    }
    Ah[ci] = *(const uint4*)ph;
    Al[ci] = *(const uint4*)pl;
  }

  f32x4 acc0[TN], acc1[TN], acc2[TN];
#pragma unroll
  for (int tn = 0; tn < TN; ++tn) {
    acc0[tn] = (f32x4){0.f, 0.f, 0.f, 0.f};
    acc1[tn] = (f32x4){0.f, 0.f, 0.f, 0.f};
    acc2[tn] = (f32x4){0.f, 0.f, 0.f, 0.f};
  }
#pragma unroll
  for (int ci = 0; ci < SLOTS; ++ci) {
    union { uint4 u; short8 s; } ah, al;
    ah.u = Ah[ci]; al.u = Al[ci];
    const char* fb = bstr + ((size_t)(ks * SLOTS + ci) * TN) * 2048;
#pragma unroll
    for (int tn = 0; tn < TN; ++tn) {
      union { uint4 u; short8 s; } bh, bl;
      bh.u = *(const uint4*)((const unsigned short*)(fb + (size_t)tn * 2048) + lane * 8);
      bl.u = *(const uint4*)((const unsigned short*)(fb + (size_t)tn * 2048 + 1024) + lane * 8);
      acc0[tn] = __builtin_amdgcn_mfma_f32_16x16x32_bf16(ah.s, bh.s, acc0[tn], 0, 0, 0);
      acc1[tn] = __builtin_amdgcn_mfma_f32_16x16x32_bf16(ah.s, bl.s, acc1[tn], 0, 0, 0);
      acc2[tn] = __builtin_amdgcn_mfma_f32_16x16x32_bf16(al.s, bh.s, acc2[tn], 0, 0, 0);
    }
  }
#pragma unroll
  for (int tn = 0; tn < TN; ++tn) {
    f32x4 s = acc0[tn] + acc1[tn] + acc2[tn];
    int slot = (tm * TN + tn) * NSPLIT + ks;
    *(f32x4*)(&red[slot * 256 + lane * 4]) = s;
  }
}

// reduce partials + run epilogue per COLUMN-PAIR (col, col+1)
template <int TM, int TN, int NSPLIT, typename F>
__device__ __forceinline__ void epi2(const float* red, int row0loc, int col0, F f) {
  for (int idx = threadIdx.x; idx < TM * TN * 128; idx += TPB) {
    int tg = idx >> 7;
    int r  = (idx >> 3) & 15;
    int cp = idx & 7;
    int e0 = (((((r >> 2) << 4) | (cp << 1)) << 2) | (r & 3));
    float z0 = 0.f, z1 = 0.f;
#pragma unroll
    for (int s = 0; s < NSPLIT; ++s) {
      const float* rp = red + (tg * NSPLIT + s) * 256;
      z0 += rp[e0];
      z1 += rp[e0 + 4];
    }
    int tm = tg / TN, tn = tg % TN;
    f(row0loc + 16 * tm + r, col0 + 16 * tn + cp * 2, z0, z1);
  }
}

// ---------------- shared pointer helpers -----------------------------------
struct Ptrs {
  unsigned short *xhi, *xlo, *rh1hi, *rh1lo, *rh2hi, *rh2lo, *hidhi, *hidlo;
  float *g1u, *g2u;
};
__device__ __forceinline__ Ptrs mkptrs(char* wsb) {
  Ptrs p;
  p.xhi = (unsigned short*)(wsb + OFF_XHI);
  p.xlo = (unsigned short*)(wsb + OFF_XLO);
  p.rh1hi = (unsigned short*)(wsb + OFF_RH1);
  p.rh1lo = (unsigned short*)(wsb + OFF_RH1 + 262144);
  p.rh2hi = (unsigned short*)(wsb + OFF_RH2);
  p.rh2lo = (unsigned short*)(wsb + OFF_RH2 + 262144);
  p.hidhi = (unsigned short*)(wsb + OFF_HID);
  p.hidlo = (unsigned short*)(wsb + OFF_HID + 131072);
  p.g1u = (float*)(wsb + OFF_G1U);
  p.g2u = (float*)(wsb + OFF_G2U);
  return p;
}
__device__ __forceinline__ unsigned short* hplane(char* wsb, int parity) {
  return (unsigned short*)(wsb + OFF_HP + (size_t)parity * 4 * HPB);
}

// P1 body (shared by k_p1 and k_s3): step index ts, parity ps = ts&1.
__device__ __forceinline__ void p1_body(char* wsb, const float* __restrict__ bg1,
                                        int ts, int m, int n, float* red) {
  const int row0 = m * 32;
  const int ps = ts & 1;
  Ptrs pp = mkptrs(wsb);
  unsigned short* h1hi_p = hplane(wsb, ps);
  unsigned short* h1lo_p = h1hi_p + 131072;
  const char* wg1s = (const char*)(wsb + OFF_WG1S + (size_t)n * 81920);
  mm_core<2, 2, 4, 5, 64>(pp.xhi, pp.xlo, 8192, ts * 64, h1hi_p, h1lo_p, 512,
                          wg1s, red, row0);
  __syncthreads();
  epi2<2, 2, 4>(red, row0, n * 32, [&](int row, int col, float z0, float z1) {
    z0 += bg1[col]; z1 += bg1[col + 1];
    float s0 = sigmoidf_(z0), s1 = sigmoidf_(z1);
    if (col < 512) {
      size_t ix = (size_t)row * 512 + col;
      unsigned hw = *(const unsigned*)(h1hi_p + ix);
      unsigned lw = *(const unsigned*)(h1lo_p + ix);
      float h0 = bf_f(hw) + bf_f(lw);
      float h1v = bf_fh(hw) + bf_fh(lw);
      float r0 = s0 * h0, r1 = s1 * h1v;
      unsigned short a0 = bf_hi(r0), a1 = bf_hi(r1);
      *(unsigned*)(pp.rh1hi + ix) = (unsigned)a0 | ((unsigned)a1 << 16);
      *(unsigned*)(pp.rh1lo + ix) = (unsigned)bf_lo(r0, a0) | ((unsigned)bf_lo(r1, a1) << 16);
    } else {
      float2 g = {s0, s1};
      *(float2*)(pp.g1u + (size_t)row * 512 + (col - 512)) = g;
    }
  });
}

// ---------------- kernels --------------------------------------------------
extern "C" __global__ __launch_bounds__(TPB, 2)
void k_prolog(const float* __restrict__ frames,
              const float* __restrict__ Wg1, const float* __restrict__ Wc1,
              const float* __restrict__ Wg2, const float* __restrict__ Wc2,
              const float* __restrict__ Wh, const float* __restrict__ Wp,
              char* __restrict__ wsb) {
  const int tid = threadIdx.x;
  const int wg = blockIdx.x;
  unsigned short* xhi = (unsigned short*)(wsb + OFF_XHI);
  unsigned short* xlo = (unsigned short*)(wsb + OFF_XLO);
  const size_t base = (size_t)wg * 8192;
  for (int i = tid; i < 8192; i += TPB) {
    float v = frames[base + i];
    unsigned short h = bf_hi(v);
    xhi[base + i] = h;
    xlo[base + i] = bf_lo(v, h);
  }
  if (wg < 32) {
    writeStream(Wg1, 1024, wg * 32, wsb + OFF_WG1S + (size_t)wg * 81920, 4, 5, 2, 18);
    writeStream(Wc1, 512, wg * 16, wsb + OFF_WC1S + (size_t)wg * 40960, 4, 5, 1, 18);
    writeStream(Wg2, 1024, wg * 32, wsb + OFF_WG2S + (size_t)wg * 131072, 4, 8, 2, 32);
    writeStream(Wc2, 512, wg * 16, wsb + OFF_WC2S + (size_t)wg * 65536, 4, 8, 1, 32);
  }
  if (wg < 16) writeStream(Wh, 256, wg * 16, wsb + OFF_WHS + (size_t)wg * 32768, 8, 2, 1, 16);
  if (wg < 4)  writeStream(Wp, 64, wg * 16, wsb + OFF_WPS + (size_t)wg * 16384, 8, 1, 1, 8);
}

extern "C" __global__ __launch_bounds__(TPB, 2)
void k_p1(char* __restrict__ wsb, const float* __restrict__ bg1, int t) {
  __shared__ float red[4096];
  const int wg = blockIdx.x;
  p1_body(wsb, bg1, t, wg >> 5, wg & 31, red);
}

// S1 = P2 (t<T_) + P2b (t>0)
extern "C" __global__ __launch_bounds__(TPB, 2)
void k_s1(char* __restrict__ wsb, const float* __restrict__ bc1,
          const float* __restrict__ bh, int t) {
  __shared__ float red[4096];
  const int wg = blockIdx.x;
  const int m = wg >> 5, n = wg & 31;
  const int row0 = m * 32;
  const int p = t & 1, q = p ^ 1;
  Ptrs pp = mkptrs(wsb);
  unsigned short* h1hi_p = hplane(wsb, p);
  unsigned short* h1lo_p = h1hi_p + 131072;
  unsigned short* h2hi_p = h1hi_p + 262144;
  unsigned short* h2lo_p = h1hi_p + 393216;
  unsigned short* h1hi_q = hplane(wsb, q);
  unsigned short* h1lo_q = h1hi_q + 131072;
  const char* wc1s = (const char*)(wsb + OFF_WC1S + (size_t)n * 40960);
  const int b2 = n & 15, a2 = n >> 4;
  const char* whs = (const char*)(wsb + OFF_WHS + (size_t)b2 * 32768);

  if (t < T_)
    mm_core<2, 1, 4, 5, 64>(pp.xhi, pp.xlo, 8192, t * 64, pp.rh1hi, pp.rh1lo, 512,
                            wc1s, red, row0);
  if (t > 0)
    mm_core<1, 1, 8, 2, 512>(h2hi_p, h2lo_p, 512, 0, nullptr, nullptr, 0,
                             whs, red + 2048, row0 + 16 * a2);
  __syncthreads();
  if (t < T_) {
    epi2<2, 1, 4>(red, row0, n * 16, [&](int row, int col, float z0, float z1) {
      z0 += bc1[col]; z1 += bc1[col + 1];
      float c0 = tanhf_(z0), c1 = tanhf_(z1);
      size_t ix = (size_t)row * 512 + col;
      float2 ug = *(const float2*)(pp.g1u + ix);
      unsigned hw = *(const unsigned*)(h1hi_p + ix);
      unsigned lw = *(const unsigned*)(h1lo_p + ix);
      float h0 = bf_f(hw) + bf_f(lw);
      float h1v = bf_fh(hw) + bf_fh(lw);
      float n0 = ug.x * h0 + (1.f - ug.x) * c0;
      float n1 = ug.y * h1v + (1.f - ug.y) * c1;
      unsigned short a0 = bf_hi(n0), a1 = bf_hi(n1);
      *(unsigned*)(h1hi_q + ix) = (unsigned)a0 | ((unsigned)a1 << 16);
      *(unsigned*)(h1lo_q + ix) = (unsigned)bf_lo(n0, a0) | ((unsigned)bf_lo(n1, a1) << 16);
    });
  }
  if (t > 0) {
    epi2<1, 1, 8>(red + 2048, row0 + 16 * a2, 16 * b2,
                  [&](int row, int col, float z0, float z1) {
      z0 += bh[col]; z1 += bh[col + 1];
      float e0v = z0 > 0.f ? z0 : __expf(z0) - 1.f;
      float e1v = z1 > 0.f ? z1 : __expf(z1) - 1.f;
      size_t ix = (size_t)row * 256 + col;
      unsigned short a0 = bf_hi(e0v), a1 = bf_hi(e1v);
      *(unsigned*)(pp.hidhi + ix) = (unsigned)a0 | ((unsigned)a1 << 16);
      *(unsigned*)(pp.hidlo + ix) = (unsigned)bf_lo(e0v, a0) | ((unsigned)bf_lo(e1v, a1) << 16);
    });
  }
}

// S2 = P3 (t<T_) + P4b (t>0, n<8)
extern "C" __global__ __launch_bounds__(TPB, 2)
void k_s2(char* __restrict__ wsb, const float* __restrict__ bg2,
          const float* __restrict__ bp, float* __restrict__ out, int t) {
  __shared__ float red[6144];
  const int wg = blockIdx.x;
  const int m = wg >> 5, n = wg & 31;
  const int row0 = m * 32;
  const int p = t & 1, q = p ^ 1;
  Ptrs pp = mkptrs(wsb);
  unsigned short* h1hi_p = hplane(wsb, p);
  unsigned short* h2hi_p = h1hi_p + 262144;
  unsigned short* h2lo_p = h1hi_p + 393216;
  unsigned short* h1hi_q = hplane(wsb, q);
  unsigned short* h1lo_q = h1hi_q + 131072;
  const char* wg2s = (const char*)(wsb + OFF_WG2S + (size_t)n * 131072);
  const int b4 = n & 3, a4 = (n >> 2) & 1;
  const char* wps = (const char*)(wsb + OFF_WPS + (size_t)b4 * 16384);

  if (t < T_)
    mm_core<2, 2, 4, 8, 512>(h1hi_q, h1lo_q, 512, 0, h2hi_p, h2lo_p, 512,
                             wg2s, red, row0);
  if (t > 0 && n < 8)
    mm_core<1, 1, 8, 1, 256>(pp.hidhi, pp.hidlo, 256, 0, nullptr, nullptr, 0,
                             wps, red + 4096, row0 + 16 * a4);
  __syncthreads();
  if (t < T_) {
    epi2<2, 2, 4>(red, row0, n * 32, [&](int row, int col, float z0, float z1) {
      z0 += bg2[col]; z1 += bg2[col + 1];
      float s0 = sigmoidf_(z0), s1 = sigmoidf_(z1);
      if (col < 512) {
        size_t ix = (size_t)row * 512 + col;
        unsigned hw = *(const unsigned*)(h2hi_p + ix);
        unsigned lw = *(const unsigned*)(h2lo_p + ix);
        float h0 = bf_f(hw) + bf_f(lw);
        float h1v = bf_fh(hw) + bf_fh(lw);
        float r0 = s0 * h0, r1 = s1 * h1v;
        unsigned short a0 = bf_hi(r0), a1 = bf_hi(r1);
        *(unsigned*)(pp.rh2hi + ix) = (unsigned)a0 | ((unsigned)a1 << 16);
        *(unsigned*)(pp.rh2lo + ix) = (unsigned)bf_lo(r0, a0) | ((unsigned)bf_lo(r1, a1) << 16);
      } else {
        float2 g = {s0, s1};
        *(float2*)(pp.g2u + (size_t)row * 512 + (col - 512)) = g;
      }
    });
  }
  if (t > 0 && n < 8) {
    epi2<1, 1, 8>(red + 4096, row0 + 16 * a4, 16 * b4,
                  [&](int row, int col, float z0, float z1) {
      float2 v = {z0 + bp[col], z1 + bp[col + 1]};
      *(float2*)(out + (size_t)row * 8192 + (size_t)(t - 1) * 64 + col) = v;
    });
  }
}

// S3 = P4 (t<T_) + P1(t+1) (t+1<T_)
extern "C" __global__ __launch_bounds__(TPB, 2)
void k_s3(char* __restrict__ wsb, const float* __restrict__ bc2,
          const float* __restrict__ bg1, int t) {
  __shared__ float red[6144];
  const int wg = blockIdx.x;
  const int m = wg >> 5, n = wg & 31;
  const int row0 = m * 32;
  const int p = t & 1, q = p ^ 1;
  Ptrs pp = mkptrs(wsb);
  unsigned short* h1hi_p = hplane(wsb, p);
  unsigned short* h2hi_p = h1hi_p + 262144;
  unsigned short* h2lo_p = h1hi_p + 393216;
  unsigned short* h1hi_q = hplane(wsb, q);
  unsigned short* h1lo_q = h1hi_q + 131072;
  unsigned short* h2hi_q = h1hi_q + 262144;
  unsigned short* h2lo_q = h1hi_q + 393216;
  const char* wc2s = (const char*)(wsb + OFF_WC2S + (size_t)n * 65536);

  mm_core<2, 1, 4, 8, 512>(h1hi_q, h1lo_q, 512, 0, pp.rh2hi, pp.rh2lo, 512,
                           wc2s, red, row0);
  __syncthreads();
  epi2<2, 1, 4>(red, row0, n * 16, [&](int row, int col, float z0, float z1) {
    z0 += bc2[col]; z1 += bc2[col + 1];
    float c0 = tanhf_(z0), c1 = tanhf_(z1);
    size_t ix = (size_t)row * 512 + col;
    float2 ug = *(const float2*)(pp.g2u + ix);
    unsigned hw = *(const unsigned*)(h2hi_p + ix);
    unsigned lw = *(const unsigned*)(h2lo_p + ix);
    float h0 = bf_f(hw) + bf_f(lw);
    float h1v = bf_fh(hw) + bf_fh(lw);
    float n0 = ug.x * h0 + (1.f - ug.x) * c0;
    float n1 = ug.y * h1v + (1.f - ug.y) * c1;
    unsigned short a0 = bf_hi(n0), a1 = bf_hi(n1);
    *(unsigned*)(h2hi_q + ix) = (unsigned)a0 | ((unsigned)a1 << 16);
    *(unsigned*)(h2lo_q + ix) = (unsigned)bf_lo(n0, a0) | ((unsigned)bf_lo(n1, a1) << 16);
  });
  // P1 for step t+1 (reads h1 plane q written by k_s1(t); disjoint outputs).
  if (t + 1 < T_) {
    __syncthreads();
    p1_body(wsb, bg1, t + 1, m, n, red + 2048);
  }
}

// ======================= R2 fallback (proven fp32 path) ====================
constexpr size_t F_SZ_H   = (size_t)N_ * U_;
constexpr size_t F_OFF_H1 = 0;
constexpr size_t F_OFF_H2 = F_OFF_H1 + 2 * F_SZ_H;
constexpr size_t F_OFF_BAR = F_OFF_H2 + 2 * F_SZ_H;
constexpr size_t F_OFF_G1 = F_OFF_BAR + 64;
constexpr size_t F_OFF_G2 = F_OFF_G1 + (size_t)N_ * 1024;
constexpr size_t F_OFF_HID = F_OFF_G2 + (size_t)N_ * 1024;
constexpr int LDP = 257;

__device__ __forceinline__ void gbarF(unsigned* b, unsigned np) {
  __syncthreads();
  if (threadIdx.x == 0) {
    __threadfence();
    unsigned e = __hip_atomic_load(b + 16, __ATOMIC_RELAXED, __HIP_MEMORY_SCOPE_AGENT);
    unsigned a = __hip_atomic_fetch_add(b, 1u, __ATOMIC_ACQ_REL, __HIP_MEMORY_SCOPE_AGENT);
    if (a == np - 1) {
      __hip_atomic_store(b, 0u, __ATOMIC_RELAXED, __HIP_MEMORY_SCOPE_AGENT);
      __hip_atomic_store(b + 16, e + 1u, __ATOMIC_RELEASE, __HIP_MEMORY_SCOPE_AGENT);
    } else {
      unsigned spins = 0;
      while (__hip_atomic_load(b + 16, __ATOMIC_RELAXED, __HIP_MEMORY_SCOPE_AGENT) == e) {
        __builtin_amdgcn_s_sleep(1);
        if (++spins > (1u << 20)) break;
      }
    }
    __threadfence();
  }
  __syncthreads();
}

template <int CK, bool GATED>
__device__ __forceinline__ void stage(float (*lds)[LDP],
                                      const float* __restrict__ src, int sStride, int sOff,
                                      const float* __restrict__ gate, int gStride, int gOff,
                                      int row0) {
  constexpr int PER = CK / 16;
  const int r = threadIdx.x >> 4;
  const int c0 = (threadIdx.x & 15) * PER;
  const float* s = src + (size_t)(row0 + r) * sStride + sOff + c0;
  float4 a0, a1, a2, a3;
  a0 = *(const float4*)(s);
  if constexpr (PER >= 8) a1 = *(const float4*)(s + 4);
  if constexpr (PER >= 16) { a2 = *(const float4*)(s + 8); a3 = *(const float4*)(s + 12); }
  if constexpr (GATED) {
    const float* g = gate + (size_t)(row0 + r) * gStride + gOff + c0;
    float4 g0 = *(const float4*)(g);
    a0.x *= g0.x; a0.y *= g0.y; a0.z *= g0.z; a0.w *= g0.w;
    if constexpr (PER >= 8) {
      float4 g1v = *(const float4*)(g + 4);
      a1.x *= g1v.x; a1.y *= g1v.y; a1.z *= g1v.z; a1.w *= g1v.w;
    }
    if constexpr (PER >= 16) {
      float4 g2v = *(const float4*)(g + 8);
      float4 g3v = *(const float4*)(g + 12);
      a2.x *= g2v.x; a2.y *= g2v.y; a2.z *= g2v.z; a2.w *= g2v.w;
      a3.x *= g3v.x; a3.y *= g3v.y; a3.z *= g3v.z; a3.w *= g3v.w;
    }
  }
  float* d = &lds[r][c0];
  d[0] = a0.x; d[1] = a0.y; d[2] = a0.z; d[3] = a0.w;
  if constexpr (PER >= 8) { d[4] = a1.x; d[5] = a1.y; d[6] = a1.z; d[7] = a1.w; }
  if constexpr (PER >= 16) {
    d[8] = a2.x; d[9] = a2.y; d[10] = a2.z; d[11] = a2.w;
    d[12] = a3.x; d[13] = a3.y; d[14] = a3.z; d[15] = a3.w;
  }
}
template <int CK>
__device__ __forceinline__ void fma2(float2& acc, const float (*lds)[LDP], int row,
                                     const float* __restrict__ B, int ldB) {
#pragma unroll 8
  for (int k = 0; k < CK; ++k) {
    const float a = lds[row][k];
    const float2 b = *(const float2*)(B + (size_t)k * ldB);
    acc.x = fmaf(a, b.x, acc.x);
    acc.y = fmaf(a, b.y, acc.y);
  }
}
template <int CK>
__device__ __forceinline__ void fma1(float& acc, const float (*lds)[LDP], int row,
                                     const float* __restrict__ B, int ldB) {
#pragma unroll 8
  for (int k = 0; k < CK; ++k) acc = fmaf(lds[row][k], B[(size_t)k * ldB], acc);
}

extern "C" __global__ __launch_bounds__(TPB, 2)
void gru_persistent(const float* __restrict__ frames,
                    const float* __restrict__ Wg1, const float* __restrict__ bg1,
                    const float* __restrict__ Wc1, const float* __restrict__ bc1,
                    const float* __restrict__ Wg2, const float* __restrict__ bg2,
                    const float* __restrict__ Wc2, const float* __restrict__ bc2,
                    const float* __restrict__ Wh,  const float* __restrict__ bh,
                    const float* __restrict__ Wp,  const float* __restrict__ bp,
                    float* __restrict__ out, float* __restrict__ ws) {
  __shared__ float lds[32][LDP];
  float* h1b = ws + F_OFF_H1;
  float* h2b = ws + F_OFF_H2;
  unsigned* bar = (unsigned*)(ws + F_OFF_BAR);
  float* g1 = ws + F_OFF_G1;
  float* g2 = ws + F_OFF_G2;
  float* hid = ws + F_OFF_HID;
  const int tid = threadIdx.x;
  const int wg = blockIdx.x;
  const int xcd = wg & 7, grp = wg >> 3;
  const int m_blk = grp >> 2, n_blk = (xcd << 2) | (grp & 3);
  const int row0 = m_blk * 32;
  const int rowA = tid & 31, cq = tid >> 5;
  const int nrow = row0 + rowA;
  for (int t = 0; t <= T_; ++t) {
    const int p = t & 1;
    const float* h1o = h1b + (size_t)p * F_SZ_H;
    float* h1n = h1b + (size_t)(p ^ 1) * F_SZ_H;
    const float* h2o = h2b + (size_t)p * F_SZ_H;
    float* h2n = h2b + (size_t)(p ^ 1) * F_SZ_H;
    if (t < T_) {
      float2 acc = {0.f, 0.f};
      const int col = n_blk * 32 + cq * 2;
      stage<64, false>(lds, frames, T_ * C_, t * C_, nullptr, 0, 0, row0);
      __syncthreads();
      fma2<64>(acc, lds, rowA, Wg1 + col, 1024);
      __syncthreads();
#pragma unroll 1
      for (int ch = 0; ch < 2; ++ch) {
        stage<256, false>(lds, h1o, U_, ch * 256, nullptr, 0, 0, row0);
        __syncthreads();
        fma2<256>(acc, lds, rowA, Wg1 + (size_t)(64 + ch * 256) * 1024 + col, 1024);
        __syncthreads();
      }
      const float2 bb = *(const float2*)(bg1 + col);
      float* gp = g1 + (size_t)nrow * 1024 + col;
      gp[0] = sigmoidf_(acc.x + bb.x);
      gp[1] = sigmoidf_(acc.y + bb.y);
    }
    gbarF(bar, NWG);
    if (t < T_) {
      float acc = 0.f;
      const int col = n_blk * 16 + cq;
      stage<64, false>(lds, frames, T_ * C_, t * C_, nullptr, 0, 0, row0);
      __syncthreads();
      fma1<64>(acc, lds, rowA, Wc1 + col, U_);
      __syncthreads();
#pragma unroll 1
      for (int ch = 0; ch < 2; ++ch) {
        stage<256, true>(lds, h1o, U_, ch * 256, g1, 1024, ch * 256, row0);
        __syncthreads();
        fma1<256>(acc, lds, rowA, Wc1 + (size_t)(64 + ch * 256) * U_ + col, U_);
        __syncthreads();
      }
      const float cv = tanhf_(acc + bc1[col]);
      const float u = g1[(size_t)nrow * 1024 + 512 + col];
      const float ho = h1o[(size_t)nrow * U_ + col];
      h1n[(size_t)nrow * U_ + col] = u * ho + (1.f - u) * cv;
    }
    if (t > 0) {
      float acc = 0.f;
      const int col = n_blk * 8 + (cq & 7);
      const bool act = tid < 256;
#pragma unroll 1
      for (int ch = 0; ch < 2; ++ch) {
        stage<256, false>(lds, h2o, U_, ch * 256, nullptr, 0, 0, row0);
        __syncthreads();
        if (act) fma1<256>(acc, lds, rowA, Wh + (size_t)(ch * 256) * H_ + col, H_);
        __syncthreads();
      }
      if (act) {
        const float z = acc + bh[col];
        hid[(size_t)nrow * H_ + col] = z > 0.f ? z : __expf(z) - 1.f;
      }
    }
    gbarF(bar, NWG);
    if (t < T_) {
      float2 acc = {0.f, 0.f};
      const int col = n_blk * 32 + cq * 2;
#pragma unroll 1
      for (int ch = 0; ch < 4; ++ch) {
        const float* src = (ch < 2) ? h1n : h2o;
        stage<256, false>(lds, src, U_, (ch & 1) * 256, nullptr, 0, 0, row0);
        __syncthreads();
        fma2<256>(acc, lds, rowA, Wg2 + (size_t)(ch * 256) * 1024 + col, 1024);
        __syncthreads();
      }
      const float2 bb = *(const float2*)(bg2 + col);
      float* gp = g2 + (size_t)nrow * 1024 + col;
      gp[0] = sigmoidf_(acc.x + bb.x);
      gp[1] = sigmoidf_(acc.y + bb.y);
    }
    gbarF(bar, NWG);
    if (t < T_) {
      float acc = 0.f;
      const int col = n_blk * 16 + cq;
#pragma unroll 1
      for (int ch = 0; ch < 4; ++ch) {
        if (ch < 2) stage<256, false>(lds, h1n, U_, (ch & 1) * 256, nullptr, 0, 0, row0);
        else stage<256, true>(lds, h2o, U_, (ch & 1) * 256, g2, 1024, (ch & 1) * 256, row0);
        __syncthreads();
        fma1<256>(acc, lds, rowA, Wc2 + (size_t)(ch * 256) * U_ + col, U_);
        __syncthreads();
      }
      const float cv = tanhf_(acc + bc2[col]);
      const float u = g2[(size_t)nrow * 1024 + 512 + col];
      const float ho = h2o[(size_t)nrow * U_ + col];
      h2n[(size_t)nrow * U_ + col] = u * ho + (1.f - u) * cv;
    }
    if (t > 0) {
      if (tid < 64) {
        float acc = 0.f;
        const int col = n_blk * 2 + cq;
        const float* hrow = hid + (size_t)nrow * H_;
#pragma unroll 8
        for (int k = 0; k < H_; ++k) acc = fmaf(hrow[k], Wp[(size_t)k * C_ + col], acc);
        out[(size_t)nrow * (T_ * C_) + (size_t)(t - 1) * C_ + col] = acc + bp[col];
      }
    }
  }
}

// ---------------- launch ---------------------------------------------------
extern "C" void kernel_launch(void* const* d_in, const int* in_sizes, int n_in,
                              void* d_out, int out_size, void* d_ws, size_t ws_size,
                              hipStream_t stream) {
  const float* frames = (const float*)d_in[0];
  const float* Wg1 = (const float*)d_in[1];
  const float* bg1 = (const float*)d_in[2];
  const float* Wc1 = (const float*)d_in[3];
  const float* bc1 = (const float*)d_in[4];
  const float* Wg2 = (const float*)d_in[5];
  const float* bg2 = (const float*)d_in[6];
  const float* Wc2 = (const float*)d_in[7];
  const float* bc2 = (const float*)d_in[8];
  const float* Wh = (const float*)d_in[9];
  const float* bh = (const float*)d_in[10];
  const float* Wp = (const float*)d_in[11];
  const float* bp = (const float*)d_in[12];
  float* out = (float*)d_out;

  if (ws_size >= WS_NEED) {
    char* wsb = (char*)d_ws;
    hipMemsetAsync(d_ws, 0, 16384 + 4 * HPB, stream);  // zero h-plane buffer 0
    hipLaunchKernelGGL(k_prolog, dim3(NWG), dim3(TPB), 0, stream,
                       frames, Wg1, Wc1, Wg2, Wc2, Wh, Wp, wsb);
    hipLaunchKernelGGL(k_p1, dim3(NWG), dim3(TPB), 0, stream, wsb, bg1, 0);
    for (int t = 0; t <= T_; ++t) {
      hipLaunchKernelGGL(k_s1, dim3(NWG), dim3(TPB), 0, stream, wsb, bc1, bh, t);
      hipLaunchKernelGGL(k_s2, dim3(NWG), dim3(TPB), 0, stream, wsb, bg2, bp, out, t);
      if (t < T_)
        hipLaunchKernelGGL(k_s3, dim3(NWG), dim3(TPB), 0, stream, wsb, bc2, bg1, t);
    }
  } else {
    float* ws = (float*)d_ws;
    hipMemsetAsync(d_ws, 0, F_OFF_G1 * sizeof(float), stream);
    void* args[] = {(void*)&frames, (void*)&Wg1, (void*)&bg1, (void*)&Wc1, (void*)&bc1,
                    (void*)&Wg2, (void*)&bg2, (void*)&Wc2, (void*)&bc2,
                    (void*)&Wh, (void*)&bh, (void*)&Wp, (void*)&bp,
                    (void*)&out, (void*)&ws};
    hipError_t err = hipLaunchCooperativeKernel((const void*)gru_persistent,
                                                dim3(NWG), dim3(TPB), args, 0, stream);
    if (err != hipSuccess) {
      (void)hipGetLastError();
      hipLaunchKernelGGL(gru_persistent, dim3(NWG), dim3(TPB), 0, stream,
                         frames, Wg1, bg1, Wc1, bc1, Wg2, bg2, Wc2, bc2,
                         Wh, bh, Wp, bp, out, ws);
    }
  }
}